// Round 1
// baseline (15350.464 us; speedup 1.0000x reference)
//
#include <hip/hip_runtime.h>
#include <math.h>

#define ALPHA 0.466f
#define T_FRAMES 200
#define HOPW 120
#define NSAMP 24000
#define M1 40
#define HID 256
#define CONDW 192

// ---------------------------------------------------------------------------
// Kernel A: frame-rate feature MLP + prenets + mc2b  -> bcoef[8][200][40]
// filters 0..3 = periodic path (b_p) for batch 0..3, 4..7 = aperiodic (b_a)
// ---------------------------------------------------------------------------
__global__ __launch_bounds__(256) void embed_kernel(
    const float* __restrict__ mceps, const float* __restrict__ apdcs,
    const float* __restrict__ f0s,
    const float* __restrict__ Wm, const float* __restrict__ bm,
    const float* __restrict__ Wa, const float* __restrict__ ba,
    const float* __restrict__ Wf, const float* __restrict__ bf,
    const float* __restrict__ Wpa, const float* __restrict__ bpa,
    const float* __restrict__ Wpp, const float* __restrict__ bpp,
    const float* __restrict__ Wrp, const float* __restrict__ brp,
    const float* __restrict__ Wra, const float* __restrict__ bra,
    const float* __restrict__ Wap, float* __restrict__ bcoef)
{
    __shared__ float s_mc[M1];
    __shared__ float s_ap[5];
    __shared__ float s_f0;
    __shared__ float s_h[HID];
    __shared__ float s_ca[CONDW];
    __shared__ float s_cp[CONDW];
    __shared__ float s_mcp[M1];
    __shared__ float s_mca[M1];

    const int bt = blockIdx.x;
    const int batch = bt / T_FRAMES;
    const int t = bt - batch * T_FRAMES;
    const int tid = threadIdx.x;

    if (tid < M1) s_mc[tid] = mceps[(batch * T_FRAMES + t) * M1 + tid];
    if (tid < 5)  s_ap[tid] = apdcs[(batch * T_FRAMES + t) * 5 + tid];
    if (tid == 0) s_f0 = f0s[batch * T_FRAMES + t];
    __syncthreads();

    // hs = mc@Wm + bm + ap@Wa + ba + f0@Wf + bf  (thread tid = hidden unit)
    {
        float acc = bm[tid] + ba[tid] + bf[tid];
        #pragma unroll 8
        for (int k = 0; k < M1; ++k) acc += s_mc[k] * Wm[k * HID + tid];
        #pragma unroll
        for (int k = 0; k < 5; ++k)  acc += s_ap[k] * Wa[k * HID + tid];
        acc += s_f0 * Wf[tid];
        s_h[tid] = acc;
    }
    __syncthreads();

    if (tid < CONDW) {
        float aA = bpa[tid];
        float aP = bpp[tid];
        #pragma unroll 8
        for (int k = 0; k < HID; ++k) {
            float h = s_h[k];
            aA += h * Wpa[k * CONDW + tid];
            aP += h * Wpp[k * CONDW + tid];
        }
        s_ca[tid] = aA;
        s_cp[tid] = aP;
    }
    __syncthreads();

    if (tid < M1) {
        float rp = brp[tid];
        float ra = bra[tid];
        #pragma unroll 8
        for (int k = 0; k < CONDW; ++k) {
            rp += s_cp[k] * Wrp[k * M1 + tid];
            ra += s_ca[k] * Wra[k * M1 + tid];
        }
        float aw = 0.f;
        #pragma unroll
        for (int k = 0; k < 5; ++k) aw += s_ap[k] * Wap[k * M1 + tid];
        s_mcp[tid] = s_mc[tid] + 0.1f * tanhf(rp);
        s_mca[tid] = s_mc[tid] + 0.1f * tanhf(ra) + aw;
    }
    __syncthreads();

    // mc2b: b[39]=mc[39]; b[m]=mc[m]-alpha*b[m+1]
    if (tid < 2) {
        const float* src = tid ? s_mca : s_mcp;
        float* dst = bcoef + ((tid * 4 + batch) * T_FRAMES + t) * M1;
        float prev = src[M1 - 1];
        dst[M1 - 1] = prev;
        for (int m = M1 - 2; m >= 0; --m) {
            prev = src[m] - ALPHA * prev;
            dst[m] = prev;
        }
    }
}

// ---------------------------------------------------------------------------
// Kernel B: per-(batch,frame) f0 -> phase base (f64 serial scan), step, amp
// ---------------------------------------------------------------------------
__global__ __launch_bounds__(64) void f0_kernel(const float* __restrict__ f0s,
    double* __restrict__ based, double* __restrict__ stepd,
    float* __restrict__ ampf)
{
    int b = threadIdx.x;
    if (b >= 4) return;
    double acc = 0.0;
    for (int ft = 0; ft < T_FRAMES; ++ft) {
        double fv = exp((double)f0s[b * T_FRAMES + ft] * 0.25 + 5.0);
        double st = fv / 24000.0;
        based[b * T_FRAMES + ft] = acc;
        stepd[b * T_FRAMES + ft] = st;
        // amp pre-scaled by (1 - NOISE_RATIO) = 0.5
        ampf[b * T_FRAMES + ft] = (float)(0.5 * sqrt(24000.0 / fmax(fv, 1.0)));
        acc += 120.0 * st;
    }
}

// ---------------------------------------------------------------------------
// Kernel D: the MLSA synthesis scan. One wave; lane = filter*4 + pade_tap.
// Filters 0..3: pulse excitation + b_p; filters 4..7: noise + b_a.
// out[b][n] = y(filter b) + y(filter b+4).
// ---------------------------------------------------------------------------
__global__ __launch_bounds__(64) void mlsa_kernel(
    const float* __restrict__ bcoef, const double* __restrict__ based,
    const double* __restrict__ stepd, const float* __restrict__ ampf,
    const float* __restrict__ noise, float* __restrict__ out)
{
    __shared__ float sexc[8 * HOPW];

    const int tid = threadIdx.x;
    const int f = (tid >> 2) & 7;   // lanes 32..63 mirror 0..31 (harmless)
    const int p = tid & 3;

    const float AA = 1.0f - ALPHA * ALPHA;
    const float P1 = 0.4999273f, P2 = 0.1067005f, P3 = 0.00956526f, P4 = 0.0003041358f;
    const float myPade = (p == 0) ? P1 : (p == 1) ? P2 : (p == 2) ? P3 : P4;
    const float sgn = (p & 1) ? -1.f : 1.f;

    // ---- state (all zeros at t=0) ----
    float d[M1 + 1];                 // warped delay line for this lane's tap
    #pragma unroll
    for (int i = 0; i <= M1; ++i) d[i] = 0.f;
    float d1a1 = 0.f, d1a2 = 0.f, d1a3 = 0.f, d1a4 = 0.f;   // stage-1 (redundant per tap)
    float d1b0 = 0.f, d1b1 = 0.f, d1b2 = 0.f, d1b3 = 0.f;
    float xin = 0.f;                 // pt2[p] for this lane

    float brg[M1];

    #pragma unroll 1
    for (int ft = 0; ft < T_FRAMES; ++ft) {
        // ---- stage this frame's excitation into LDS (all 64 lanes) ----
        for (int j = tid; j < 8 * HOPW; j += 64) {
            int ff = j / HOPW;
            int k = j - ff * HOPW;
            float val;
            if (ff < 4) {
                double st = stepd[ff * T_FRAMES + ft];
                double bs = based[ff * T_FRAMES + ft];
                double ph  = bs + (double)(k + 1) * st;
                double php = bs + (double)k * st;
                val = (floor(ph) > floor(php)) ? ampf[ff * T_FRAMES + ft] : 0.0f;
            } else {
                val = 0.5f * noise[(ff - 4) * NSAMP + ft * HOPW + k];
            }
            sexc[j] = val;
        }
        __syncthreads();

        // ---- frame coefficients ----
        const float4* bb = (const float4*)(bcoef + (f * T_FRAMES + ft) * M1);
        #pragma unroll
        for (int q = 0; q < 10; ++q) {
            float4 v = bb[q];
            brg[4 * q + 0] = v.x; brg[4 * q + 1] = v.y;
            brg[4 * q + 2] = v.z; brg[4 * q + 3] = v.w;
        }
        const float G = expf(brg[0]);
        const float b1 = brg[1];

        // ---- sample loop ----
        for (int k = 0; k < HOPW; ++k) {
            float x = sexc[f * HOPW + k] * G;

            // stage 1 (SPTK mlsadf1), computed identically on all 4 tap lanes
            float na0 = AA * d1b0 + ALPHA * d1a1;
            float na1 = AA * d1b1 + ALPHA * d1a2;
            float na2 = AA * d1b2 + ALPHA * d1a3;
            float na3 = AA * d1b3 + ALPHA * d1a4;
            float n0 = na0 * b1, n1 = na1 * b1, n2 = na2 * b1, n3 = na3 * b1;
            float v10 = n0 * P1, v11 = n1 * P2, v12 = n2 * P3, v13 = n3 * P4;
            float x1 = x + ((v10 - v11) + (v12 - v13));
            float y1 = ((v10 + v11) + (v12 + v13)) + x1;
            d1a1 = na0; d1a2 = na1; d1a3 = na2; d1a4 = na3;
            d1b0 = x1;  d1b1 = n0;  d1b2 = n1;  d1b3 = n2;

            // stage 2 (SPTK mlsadf2/mlsafir), this lane's Pade tap
            float dl = AA * xin + ALPHA * d[1];
            float c[M1 - 2];
            #pragma unroll
            for (int m = 0; m < M1 - 2; ++m) c[m] = d[m + 2] + ALPHA * d[m + 3];
            float prev = dl;
            float fy = 0.f;
            #pragma unroll
            for (int m = 0; m < M1 - 2; ++m) {
                float tt = c[m] - ALPHA * prev;   // == d[m]+a*(d[m+1]-prev)
                fy += tt * brg[m + 2];
                c[m] = tt;
                prev = tt;
            }
            // delay-line shift: d' = [xin, dl, dl, dupd...]
            d[0] = xin; d[1] = dl; d[2] = dl;
            #pragma unroll
            for (int m = 0; m < M1 - 2; ++m) d[m + 3] = c[m];

            // cross-tap combine
            float t2 = fy * myPade;               // v2[p]
            float t1s = t2 + __shfl_xor(t2, 1);
            float Tsum = t1s + __shfl_xor(t1s, 2);        // sum v2
            float u0 = t2 * sgn;
            float u1 = u0 + __shfl_xor(u0, 1);
            float Usum = u1 + __shfl_xor(u1, 2);          // sum v2*SIGN
            float x2 = y1 + Usum;
            float y2 = Tsum + x2;

            // next-sample stage-2 input: pt2' = [x2, fy0, fy1, fy2]
            float fyp = __shfl_up(fy, 1, 4);
            xin = (p == 0) ? x2 : fyp;

            // periodic + aperiodic combine and store
            float yo = y2 + __shfl_xor(y2, 16);
            if (tid < 16 && p == 0) out[(tid >> 2) * NSAMP + ft * HOPW + k] = yo;
        }
        __syncthreads();
    }
}

// ---------------------------------------------------------------------------
extern "C" void kernel_launch(void* const* d_in, const int* in_sizes, int n_in,
                              void* d_out, int out_size, void* d_ws, size_t ws_size,
                              hipStream_t stream) {
    const float* mceps = (const float*)d_in[0];
    const float* apdcs = (const float*)d_in[1];
    const float* f0s   = (const float*)d_in[2];
    const float* noise = (const float*)d_in[3];
    const float* Wm  = (const float*)d_in[4];
    const float* bm  = (const float*)d_in[5];
    const float* Wa  = (const float*)d_in[6];
    const float* ba  = (const float*)d_in[7];
    const float* Wf  = (const float*)d_in[8];
    const float* bf  = (const float*)d_in[9];
    const float* Wpa = (const float*)d_in[10];
    const float* bpa = (const float*)d_in[11];
    const float* Wpp = (const float*)d_in[12];
    const float* bpp = (const float*)d_in[13];
    const float* Wrp = (const float*)d_in[14];
    const float* brp = (const float*)d_in[15];
    const float* Wra = (const float*)d_in[16];
    const float* bra = (const float*)d_in[17];
    const float* Wap = (const float*)d_in[18];
    float* out = (float*)d_out;

    char* ws = (char*)d_ws;
    double* based = (double*)(ws + 0);        // 4*200*8 = 6400 B
    double* stepd = (double*)(ws + 6400);     // 6400 B
    float*  ampf  = (float*)(ws + 12800);     // 3200 B
    float*  bcoef = (float*)(ws + 16000);     // 8*200*40*4 = 256000 B

    embed_kernel<<<dim3(4 * T_FRAMES), dim3(256), 0, stream>>>(
        mceps, apdcs, f0s, Wm, bm, Wa, ba, Wf, bf,
        Wpa, bpa, Wpp, bpp, Wrp, brp, Wra, bra, Wap, bcoef);

    f0_kernel<<<dim3(1), dim3(64), 0, stream>>>(f0s, based, stepd, ampf);

    mlsa_kernel<<<dim3(1), dim3(64), 0, stream>>>(bcoef, based, stepd, ampf, noise, out);
}

// Round 2
// 14607.222 us; speedup vs baseline: 1.0509x; 1.0509x over previous
//
#include <hip/hip_runtime.h>
#include <math.h>

#define ALPHA 0.466f
#define T_FRAMES 200
#define HOPW 120
#define NSAMP 24000
#define M1 40
#define HID 256
#define CONDW 192

// ---------------------------------------------------------------------------
// Kernel A: frame-rate feature MLP + prenets + mc2b  -> bcoef[8][200][40]
// filters 0..3 = periodic path (b_p) for batch 0..3, 4..7 = aperiodic (b_a)
// ---------------------------------------------------------------------------
__global__ __launch_bounds__(256) void embed_kernel(
    const float* __restrict__ mceps, const float* __restrict__ apdcs,
    const float* __restrict__ f0s,
    const float* __restrict__ Wm, const float* __restrict__ bm,
    const float* __restrict__ Wa, const float* __restrict__ ba,
    const float* __restrict__ Wf, const float* __restrict__ bf,
    const float* __restrict__ Wpa, const float* __restrict__ bpa,
    const float* __restrict__ Wpp, const float* __restrict__ bpp,
    const float* __restrict__ Wrp, const float* __restrict__ brp,
    const float* __restrict__ Wra, const float* __restrict__ bra,
    const float* __restrict__ Wap, float* __restrict__ bcoef)
{
    __shared__ float s_mc[M1];
    __shared__ float s_ap[5];
    __shared__ float s_f0;
    __shared__ float s_h[HID];
    __shared__ float s_ca[CONDW];
    __shared__ float s_cp[CONDW];
    __shared__ float s_mcp[M1];
    __shared__ float s_mca[M1];

    const int bt = blockIdx.x;
    const int batch = bt / T_FRAMES;
    const int t = bt - batch * T_FRAMES;
    const int tid = threadIdx.x;

    if (tid < M1) s_mc[tid] = mceps[(batch * T_FRAMES + t) * M1 + tid];
    if (tid < 5)  s_ap[tid] = apdcs[(batch * T_FRAMES + t) * 5 + tid];
    if (tid == 0) s_f0 = f0s[batch * T_FRAMES + t];
    __syncthreads();

    // hs = mc@Wm + bm + ap@Wa + ba + f0@Wf + bf  (thread tid = hidden unit)
    {
        float acc = bm[tid] + ba[tid] + bf[tid];
        #pragma unroll 8
        for (int k = 0; k < M1; ++k) acc += s_mc[k] * Wm[k * HID + tid];
        #pragma unroll
        for (int k = 0; k < 5; ++k)  acc += s_ap[k] * Wa[k * HID + tid];
        acc += s_f0 * Wf[tid];
        s_h[tid] = acc;
    }
    __syncthreads();

    if (tid < CONDW) {
        float aA = bpa[tid];
        float aP = bpp[tid];
        #pragma unroll 8
        for (int k = 0; k < HID; ++k) {
            float h = s_h[k];
            aA += h * Wpa[k * CONDW + tid];
            aP += h * Wpp[k * CONDW + tid];
        }
        s_ca[tid] = aA;
        s_cp[tid] = aP;
    }
    __syncthreads();

    if (tid < M1) {
        float rp = brp[tid];
        float ra = bra[tid];
        #pragma unroll 8
        for (int k = 0; k < CONDW; ++k) {
            rp += s_cp[k] * Wrp[k * M1 + tid];
            ra += s_ca[k] * Wra[k * M1 + tid];
        }
        float aw = 0.f;
        #pragma unroll
        for (int k = 0; k < 5; ++k) aw += s_ap[k] * Wap[k * M1 + tid];
        s_mcp[tid] = s_mc[tid] + 0.1f * tanhf(rp);
        s_mca[tid] = s_mc[tid] + 0.1f * tanhf(ra) + aw;
    }
    __syncthreads();

    // mc2b: b[39]=mc[39]; b[m]=mc[m]-alpha*b[m+1]
    if (tid < 2) {
        const float* src = tid ? s_mca : s_mcp;
        float* dst = bcoef + ((tid * 4 + batch) * T_FRAMES + t) * M1;
        float prev = src[M1 - 1];
        dst[M1 - 1] = prev;
        for (int m = M1 - 2; m >= 0; --m) {
            prev = src[m] - ALPHA * prev;
            dst[m] = prev;
        }
    }
}

// ---------------------------------------------------------------------------
// Kernel B: per-(batch,frame) f0 -> phase base (f64 serial scan), step, amp
// ---------------------------------------------------------------------------
__global__ __launch_bounds__(64) void f0_kernel(const float* __restrict__ f0s,
    double* __restrict__ based, double* __restrict__ stepd,
    float* __restrict__ ampf)
{
    int b = threadIdx.x;
    if (b >= 4) return;
    double acc = 0.0;
    for (int ft = 0; ft < T_FRAMES; ++ft) {
        double fv = exp((double)f0s[b * T_FRAMES + ft] * 0.25 + 5.0);
        double st = fv / 24000.0;
        based[b * T_FRAMES + ft] = acc;
        stepd[b * T_FRAMES + ft] = st;
        // amp pre-scaled by (1 - NOISE_RATIO) = 0.5
        ampf[b * T_FRAMES + ft] = (float)(0.5 * sqrt(24000.0 / fmax(fv, 1.0)));
        acc += 120.0 * st;
    }
}

// ---------------------------------------------------------------------------
// Kernel D: the MLSA synthesis scan. One wave; lane = filter*4 + pade_tap.
// Filters 0..3: pulse excitation + b_p; filters 4..7: noise + b_a.
// out[b][n] = y(filter b) + y(filter b+4).
//
// __launch_bounds__(64,1): one wave per EU -> allocator may use the full
// VGPR file; round-1 showed VGPR=76 with d[]/c[] demoted to scratch
// (~1530 cyc/sample, 5x over the issue-bound model). The delay-line update
// is done IN PLACE with a rolling carry so live state is d[41]+brg[40]+~20.
// ---------------------------------------------------------------------------
__global__ __launch_bounds__(64, 1) void mlsa_kernel(
    const float* __restrict__ bcoef, const double* __restrict__ based,
    const double* __restrict__ stepd, const float* __restrict__ ampf,
    const float* __restrict__ noise, float* __restrict__ out)
{
    __shared__ float sexc[8 * HOPW];

    const int tid = threadIdx.x;
    const int f = (tid >> 2) & 7;   // lanes 32..63 mirror 0..31 (harmless)
    const int p = tid & 3;

    const float AA = 1.0f - ALPHA * ALPHA;
    const float P1 = 0.4999273f, P2 = 0.1067005f, P3 = 0.00956526f, P4 = 0.0003041358f;
    const float myPade = (p == 0) ? P1 : (p == 1) ? P2 : (p == 2) ? P3 : P4;
    const float sgn = (p & 1) ? -1.f : 1.f;

    // ---- state (all zeros at t=0) ----
    float d[M1 + 1];                 // warped delay line for this lane's tap
    #pragma unroll
    for (int i = 0; i <= M1; ++i) d[i] = 0.f;
    float d1a1 = 0.f, d1a2 = 0.f, d1a3 = 0.f, d1a4 = 0.f;   // stage-1 (redundant per tap)
    float d1b0 = 0.f, d1b1 = 0.f, d1b2 = 0.f, d1b3 = 0.f;
    float xin = 0.f;                 // pt2[p] for this lane

    float brg[M1];

    #pragma unroll 1
    for (int ft = 0; ft < T_FRAMES; ++ft) {
        // ---- stage this frame's excitation into LDS (all 64 lanes) ----
        for (int j = tid; j < 8 * HOPW; j += 64) {
            int ff = j / HOPW;
            int k = j - ff * HOPW;
            float val;
            if (ff < 4) {
                double st = stepd[ff * T_FRAMES + ft];
                double bs = based[ff * T_FRAMES + ft];
                double ph  = bs + (double)(k + 1) * st;
                double php = bs + (double)k * st;
                val = (floor(ph) > floor(php)) ? ampf[ff * T_FRAMES + ft] : 0.0f;
            } else {
                val = 0.5f * noise[(ff - 4) * NSAMP + ft * HOPW + k];
            }
            sexc[j] = val;
        }
        __syncthreads();

        // ---- frame coefficients ----
        const float4* bb = (const float4*)(bcoef + (f * T_FRAMES + ft) * M1);
        #pragma unroll
        for (int q = 0; q < 10; ++q) {
            float4 v = bb[q];
            brg[4 * q + 0] = v.x; brg[4 * q + 1] = v.y;
            brg[4 * q + 2] = v.z; brg[4 * q + 3] = v.w;
        }
        const float G = expf(brg[0]);
        const float b1 = brg[1];

        // ---- sample loop ----
        for (int k = 0; k < HOPW; ++k) {
            float x = sexc[f * HOPW + k] * G;

            // stage 1 (SPTK mlsadf1), computed identically on all 4 tap lanes
            float na0 = AA * d1b0 + ALPHA * d1a1;
            float na1 = AA * d1b1 + ALPHA * d1a2;
            float na2 = AA * d1b2 + ALPHA * d1a3;
            float na3 = AA * d1b3 + ALPHA * d1a4;
            float n0 = na0 * b1, n1 = na1 * b1, n2 = na2 * b1, n3 = na3 * b1;
            float v10 = n0 * P1, v11 = n1 * P2, v12 = n2 * P3, v13 = n3 * P4;
            float x1 = x + ((v10 - v11) + (v12 - v13));
            float y1 = ((v10 + v11) + (v12 + v13)) + x1;
            d1a1 = na0; d1a2 = na1; d1a3 = na2; d1a4 = na3;
            d1b0 = x1;  d1b1 = n0;  d1b2 = n1;  d1b3 = n2;

            // stage 2 (SPTK mlsadf2/mlsafir), this lane's Pade tap.
            // In-place delay-line update with rolling carry (no c[] array):
            //   tt_m = old d[m+2] + a*(old d[m+3] - prev);  d'[m+3] = tt_m
            float dl = AA * xin + ALPHA * d[1];
            float prev = dl;
            float carry = d[2];
            float fyA = 0.f, fyB = 0.f;
            #pragma unroll
            for (int m = 0; m < M1 - 2; ++m) {
                float nxt = d[m + 3];
                float cm = carry + ALPHA * nxt;    // off-chain part
                float tt = cm - ALPHA * prev;      // chain: 1 FMA/link
                if (m & 1) fyB += tt * brg[m + 2];
                else       fyA += tt * brg[m + 2];
                d[m + 3] = tt;
                carry = nxt;
                prev = tt;
            }
            float fy = fyA + fyB;
            d[0] = xin; d[1] = dl; d[2] = dl;

            // cross-tap combine
            float t2 = fy * myPade;               // v2[p]
            float t1s = t2 + __shfl_xor(t2, 1);
            float Tsum = t1s + __shfl_xor(t1s, 2);        // sum v2
            float u0 = t2 * sgn;
            float u1 = u0 + __shfl_xor(u0, 1);
            float Usum = u1 + __shfl_xor(u1, 2);          // sum v2*SIGN
            float x2 = y1 + Usum;
            float y2 = Tsum + x2;

            // next-sample stage-2 input: pt2' = [x2, fy0, fy1, fy2]
            float fyp = __shfl_up(fy, 1, 4);
            xin = (p == 0) ? x2 : fyp;

            // periodic + aperiodic combine and store
            float yo = y2 + __shfl_xor(y2, 16);
            if (tid < 16 && p == 0) out[(tid >> 2) * NSAMP + ft * HOPW + k] = yo;
        }
        __syncthreads();
    }
}

// ---------------------------------------------------------------------------
extern "C" void kernel_launch(void* const* d_in, const int* in_sizes, int n_in,
                              void* d_out, int out_size, void* d_ws, size_t ws_size,
                              hipStream_t stream) {
    const float* mceps = (const float*)d_in[0];
    const float* apdcs = (const float*)d_in[1];
    const float* f0s   = (const float*)d_in[2];
    const float* noise = (const float*)d_in[3];
    const float* Wm  = (const float*)d_in[4];
    const float* bm  = (const float*)d_in[5];
    const float* Wa  = (const float*)d_in[6];
    const float* ba  = (const float*)d_in[7];
    const float* Wf  = (const float*)d_in[8];
    const float* bf  = (const float*)d_in[9];
    const float* Wpa = (const float*)d_in[10];
    const float* bpa = (const float*)d_in[11];
    const float* Wpp = (const float*)d_in[12];
    const float* bpp = (const float*)d_in[13];
    const float* Wrp = (const float*)d_in[14];
    const float* brp = (const float*)d_in[15];
    const float* Wra = (const float*)d_in[16];
    const float* bra = (const float*)d_in[17];
    const float* Wap = (const float*)d_in[18];
    float* out = (float*)d_out;

    char* ws = (char*)d_ws;
    double* based = (double*)(ws + 0);        // 4*200*8 = 6400 B
    double* stepd = (double*)(ws + 6400);     // 6400 B
    float*  ampf  = (float*)(ws + 12800);     // 3200 B
    float*  bcoef = (float*)(ws + 16000);     // 8*200*40*4 = 256000 B

    embed_kernel<<<dim3(4 * T_FRAMES), dim3(256), 0, stream>>>(
        mceps, apdcs, f0s, Wm, bm, Wa, ba, Wf, bf,
        Wpa, bpa, Wpp, bpp, Wrp, brp, Wra, bra, Wap, bcoef);

    f0_kernel<<<dim3(1), dim3(64), 0, stream>>>(f0s, based, stepd, ampf);

    mlsa_kernel<<<dim3(1), dim3(64), 0, stream>>>(bcoef, based, stepd, ampf, noise, out);
}

// Round 3
// 1857.753 us; speedup vs baseline: 8.2629x; 7.8628x over previous
//
#include <hip/hip_runtime.h>
#include <math.h>

#define ALPHA 0.466f
#define T_FRAMES 200
#define HOPW 120
#define NSAMP 24000
#define M1 40
#define HID 256
#define CONDW 192

// time-chunking of the MLSA scan: each block owns CHUNKF output frames and
// warms up from zero state over WARMF frames (filter is stable; state from
// >2400 samples back is below fp32 noise).
#define NCHUNK 20
#define CHUNKF (T_FRAMES / NCHUNK)   // 10
#define WARMF 20

// ---------------------------------------------------------------------------
// Kernel A: frame-rate feature MLP + prenets + mc2b  -> bcoef[8][200][40]
// filters 0..3 = periodic path (b_p) for batch 0..3, 4..7 = aperiodic (b_a)
// ---------------------------------------------------------------------------
__global__ __launch_bounds__(256) void embed_kernel(
    const float* __restrict__ mceps, const float* __restrict__ apdcs,
    const float* __restrict__ f0s,
    const float* __restrict__ Wm, const float* __restrict__ bm,
    const float* __restrict__ Wa, const float* __restrict__ ba,
    const float* __restrict__ Wf, const float* __restrict__ bf,
    const float* __restrict__ Wpa, const float* __restrict__ bpa,
    const float* __restrict__ Wpp, const float* __restrict__ bpp,
    const float* __restrict__ Wrp, const float* __restrict__ brp,
    const float* __restrict__ Wra, const float* __restrict__ bra,
    const float* __restrict__ Wap, float* __restrict__ bcoef)
{
    __shared__ float s_mc[M1];
    __shared__ float s_ap[5];
    __shared__ float s_f0;
    __shared__ float s_h[HID];
    __shared__ float s_ca[CONDW];
    __shared__ float s_cp[CONDW];
    __shared__ float s_mcp[M1];
    __shared__ float s_mca[M1];

    const int bt = blockIdx.x;
    const int batch = bt / T_FRAMES;
    const int t = bt - batch * T_FRAMES;
    const int tid = threadIdx.x;

    if (tid < M1) s_mc[tid] = mceps[(batch * T_FRAMES + t) * M1 + tid];
    if (tid < 5)  s_ap[tid] = apdcs[(batch * T_FRAMES + t) * 5 + tid];
    if (tid == 0) s_f0 = f0s[batch * T_FRAMES + t];
    __syncthreads();

    {
        float acc = bm[tid] + ba[tid] + bf[tid];
        #pragma unroll 8
        for (int k = 0; k < M1; ++k) acc += s_mc[k] * Wm[k * HID + tid];
        #pragma unroll
        for (int k = 0; k < 5; ++k)  acc += s_ap[k] * Wa[k * HID + tid];
        acc += s_f0 * Wf[tid];
        s_h[tid] = acc;
    }
    __syncthreads();

    if (tid < CONDW) {
        float aA = bpa[tid];
        float aP = bpp[tid];
        #pragma unroll 8
        for (int k = 0; k < HID; ++k) {
            float h = s_h[k];
            aA += h * Wpa[k * CONDW + tid];
            aP += h * Wpp[k * CONDW + tid];
        }
        s_ca[tid] = aA;
        s_cp[tid] = aP;
    }
    __syncthreads();

    if (tid < M1) {
        float rp = brp[tid];
        float ra = bra[tid];
        #pragma unroll 8
        for (int k = 0; k < CONDW; ++k) {
            rp += s_cp[k] * Wrp[k * M1 + tid];
            ra += s_ca[k] * Wra[k * M1 + tid];
        }
        float aw = 0.f;
        #pragma unroll
        for (int k = 0; k < 5; ++k) aw += s_ap[k] * Wap[k * M1 + tid];
        s_mcp[tid] = s_mc[tid] + 0.1f * tanhf(rp);
        s_mca[tid] = s_mc[tid] + 0.1f * tanhf(ra) + aw;
    }
    __syncthreads();

    if (tid < 2) {
        const float* src = tid ? s_mca : s_mcp;
        float* dst = bcoef + ((tid * 4 + batch) * T_FRAMES + t) * M1;
        float prev = src[M1 - 1];
        dst[M1 - 1] = prev;
        for (int m = M1 - 2; m >= 0; --m) {
            prev = src[m] - ALPHA * prev;
            dst[m] = prev;
        }
    }
}

// ---------------------------------------------------------------------------
// Kernel B: per-(batch,frame) f0 -> phase base (f64 serial scan), step, amp
// ---------------------------------------------------------------------------
__global__ __launch_bounds__(64) void f0_kernel(const float* __restrict__ f0s,
    double* __restrict__ based, double* __restrict__ stepd,
    float* __restrict__ ampf)
{
    int b = threadIdx.x;
    if (b >= 4) return;
    double acc = 0.0;
    for (int ft = 0; ft < T_FRAMES; ++ft) {
        double fv = exp((double)f0s[b * T_FRAMES + ft] * 0.25 + 5.0);
        double st = fv / 24000.0;
        based[b * T_FRAMES + ft] = acc;
        stepd[b * T_FRAMES + ft] = st;
        ampf[b * T_FRAMES + ft] = (float)(0.5 * sqrt(24000.0 / fmax(fv, 1.0)));
        acc += 120.0 * st;
    }
}

// ---------------------------------------------------------------------------
// Kernel D: MLSA synthesis scan, time-chunked. Block = chunk; one wave;
// lane = filter*4 + pade_tap (filters 0..3 periodic, 4..7 aperiodic).
//
// Round-2 lesson: SROA runs before the unroller, so float d[41]/brg[40]
// stayed in scratch (VGPR_Count=76, ~1460 cyc/sample). All filter state is
// now NAMED SCALARS -> guaranteed VGPR residency (~100 live floats, fits
// the 512-VGPR single-wave budget under __launch_bounds__(64,1)).
// ---------------------------------------------------------------------------
__global__ __launch_bounds__(64, 1) void mlsa_kernel(
    const float* __restrict__ bcoef, const double* __restrict__ based,
    const double* __restrict__ stepd, const float* __restrict__ ampf,
    const float* __restrict__ noise, float* __restrict__ out)
{
    __shared__ float sexc[8 * HOPW];

    const int tid = threadIdx.x;
    const int f = (tid >> 2) & 7;   // lanes 32..63 mirror 0..31 (harmless)
    const int p = tid & 3;

    const float AA = 1.0f - ALPHA * ALPHA;
    const float P1 = 0.4999273f, P2 = 0.1067005f, P3 = 0.00956526f, P4 = 0.0003041358f;
    const float myPade = (p == 0) ? P1 : (p == 1) ? P2 : (p == 2) ? P3 : P4;
    const float sgn = (p & 1) ? -1.f : 1.f;

    // ---- warped delay line d[1..40] as named scalars (d[0] is never read) ----
    float d1=0.f,d2=0.f,d3=0.f,d4=0.f,d5=0.f,d6=0.f,d7=0.f,d8=0.f,d9=0.f,d10=0.f,
          d11=0.f,d12=0.f,d13=0.f,d14=0.f,d15=0.f,d16=0.f,d17=0.f,d18=0.f,d19=0.f,d20=0.f,
          d21=0.f,d22=0.f,d23=0.f,d24=0.f,d25=0.f,d26=0.f,d27=0.f,d28=0.f,d29=0.f,d30=0.f,
          d31=0.f,d32=0.f,d33=0.f,d34=0.f,d35=0.f,d36=0.f,d37=0.f,d38=0.f,d39=0.f,d40=0.f;
    // ---- stage-1 state ----
    float d1a1 = 0.f, d1a2 = 0.f, d1a3 = 0.f, d1a4 = 0.f;
    float d1b0 = 0.f, d1b1 = 0.f, d1b2 = 0.f, d1b3 = 0.f;
    float xin = 0.f;                 // pt2[p] for this lane
    // ---- frame coefficients as named scalars ----
    float b0,b1,b2,b3,b4,b5,b6,b7,b8,b9,b10,b11,b12,b13,b14,b15,b16,b17,b18,b19,
          b20,b21,b22,b23,b24,b25,b26,b27,b28,b29,b30,b31,b32,b33,b34,b35,b36,b37,b38,b39;

    const int outF0 = blockIdx.x * CHUNKF;                       // first output frame
    const int beginF = (outF0 >= WARMF) ? (outF0 - WARMF) : 0;   // warm-up start
    const int endF = outF0 + CHUNKF;

    #pragma unroll 1
    for (int ft = beginF; ft < endF; ++ft) {
        // ---- stage this frame's excitation into LDS (all 64 lanes) ----
        for (int j = tid; j < 8 * HOPW; j += 64) {
            int ff = j / HOPW;
            int k = j - ff * HOPW;
            float val;
            if (ff < 4) {
                double st = stepd[ff * T_FRAMES + ft];
                double bs = based[ff * T_FRAMES + ft];
                double ph  = bs + (double)(k + 1) * st;
                double php = bs + (double)k * st;
                val = (floor(ph) > floor(php)) ? ampf[ff * T_FRAMES + ft] : 0.0f;
            } else {
                val = 0.5f * noise[(ff - 4) * NSAMP + ft * HOPW + k];
            }
            sexc[j] = val;
        }
        __syncthreads();

        // ---- frame coefficients ----
        {
            const float4* bb = (const float4*)(bcoef + (f * T_FRAMES + ft) * M1);
            #define LD4(i, B0,B1,B2,B3) { float4 q = bb[i]; B0=q.x; B1=q.y; B2=q.z; B3=q.w; }
            LD4(0, b0,b1,b2,b3)   LD4(1, b4,b5,b6,b7)   LD4(2, b8,b9,b10,b11)
            LD4(3, b12,b13,b14,b15) LD4(4, b16,b17,b18,b19) LD4(5, b20,b21,b22,b23)
            LD4(6, b24,b25,b26,b27) LD4(7, b28,b29,b30,b31) LD4(8, b32,b33,b34,b35)
            LD4(9, b36,b37,b38,b39)
            #undef LD4
        }
        const float G = expf(b0);
        const bool wr = (ft >= outF0) && (tid < 16) && (p == 0);
        float* outp = out + (tid >> 2) * NSAMP + ft * HOPW;

        // ---- sample loop ----
        for (int k = 0; k < HOPW; ++k) {
            float x = sexc[f * HOPW + k] * G;

            // stage 1 (SPTK mlsadf1), identical on all 4 tap lanes
            float na0 = AA * d1b0 + ALPHA * d1a1;
            float na1 = AA * d1b1 + ALPHA * d1a2;
            float na2 = AA * d1b2 + ALPHA * d1a3;
            float na3 = AA * d1b3 + ALPHA * d1a4;
            float n0 = na0 * b1, n1 = na1 * b1, n2 = na2 * b1, n3 = na3 * b1;
            float v10 = n0 * P1, v11 = n1 * P2, v12 = n2 * P3, v13 = n3 * P4;
            float x1 = x + ((v10 - v11) + (v12 - v13));
            float y1 = ((v10 + v11) + (v12 + v13)) + x1;
            d1a1 = na0; d1a2 = na1; d1a3 = na2; d1a4 = na3;
            d1b0 = x1;  d1b1 = n0;  d1b2 = n1;  d1b3 = n2;

            // stage 2 (SPTK mlsadf2/mlsafir): in-place order recurrence,
            // rolling carry, all state in named scalars.
            float dl = AA * xin + ALPHA * d1;
            float prev = dl;
            float carry = d2;
            float fyA = 0.f, fyB = 0.f;
            #define STEPA(dn, bn) { const float nxt = dn; const float cm = fmaf(ALPHA, nxt, carry); const float tt = fmaf(-ALPHA, prev, cm); fyA = fmaf(tt, bn, fyA); dn = tt; carry = nxt; prev = tt; }
            #define STEPB(dn, bn) { const float nxt = dn; const float cm = fmaf(ALPHA, nxt, carry); const float tt = fmaf(-ALPHA, prev, cm); fyB = fmaf(tt, bn, fyB); dn = tt; carry = nxt; prev = tt; }
            STEPA(d3,b2)   STEPB(d4,b3)   STEPA(d5,b4)   STEPB(d6,b5)
            STEPA(d7,b6)   STEPB(d8,b7)   STEPA(d9,b8)   STEPB(d10,b9)
            STEPA(d11,b10) STEPB(d12,b11) STEPA(d13,b12) STEPB(d14,b13)
            STEPA(d15,b14) STEPB(d16,b15) STEPA(d17,b16) STEPB(d18,b17)
            STEPA(d19,b18) STEPB(d20,b19) STEPA(d21,b20) STEPB(d22,b21)
            STEPA(d23,b22) STEPB(d24,b23) STEPA(d25,b24) STEPB(d26,b25)
            STEPA(d27,b26) STEPB(d28,b27) STEPA(d29,b28) STEPB(d30,b29)
            STEPA(d31,b30) STEPB(d32,b31) STEPA(d33,b32) STEPB(d34,b33)
            STEPA(d35,b34) STEPB(d36,b35) STEPA(d37,b36) STEPB(d38,b37)
            STEPA(d39,b38) STEPB(d40,b39)
            #undef STEPA
            #undef STEPB
            float fy = fyA + fyB;
            d1 = dl; d2 = dl;

            // cross-tap combine
            float t2 = fy * myPade;               // v2[p]
            float t1s = t2 + __shfl_xor(t2, 1);
            float Tsum = t1s + __shfl_xor(t1s, 2);        // sum v2
            float u0 = t2 * sgn;
            float u1 = u0 + __shfl_xor(u0, 1);
            float Usum = u1 + __shfl_xor(u1, 2);          // sum v2*SIGN
            float x2 = y1 + Usum;
            float y2 = Tsum + x2;

            // next-sample stage-2 input: pt2' = [x2, fy0, fy1, fy2]
            float fyp = __shfl_up(fy, 1, 4);
            xin = (p == 0) ? x2 : fyp;

            // periodic + aperiodic combine and store
            float yo = y2 + __shfl_xor(y2, 16);
            if (wr) outp[k] = yo;
        }
        __syncthreads();
    }
}

// ---------------------------------------------------------------------------
extern "C" void kernel_launch(void* const* d_in, const int* in_sizes, int n_in,
                              void* d_out, int out_size, void* d_ws, size_t ws_size,
                              hipStream_t stream) {
    const float* mceps = (const float*)d_in[0];
    const float* apdcs = (const float*)d_in[1];
    const float* f0s   = (const float*)d_in[2];
    const float* noise = (const float*)d_in[3];
    const float* Wm  = (const float*)d_in[4];
    const float* bm  = (const float*)d_in[5];
    const float* Wa  = (const float*)d_in[6];
    const float* ba  = (const float*)d_in[7];
    const float* Wf  = (const float*)d_in[8];
    const float* bf  = (const float*)d_in[9];
    const float* Wpa = (const float*)d_in[10];
    const float* bpa = (const float*)d_in[11];
    const float* Wpp = (const float*)d_in[12];
    const float* bpp = (const float*)d_in[13];
    const float* Wrp = (const float*)d_in[14];
    const float* brp = (const float*)d_in[15];
    const float* Wra = (const float*)d_in[16];
    const float* bra = (const float*)d_in[17];
    const float* Wap = (const float*)d_in[18];
    float* out = (float*)d_out;

    char* ws = (char*)d_ws;
    double* based = (double*)(ws + 0);        // 4*200*8 = 6400 B
    double* stepd = (double*)(ws + 6400);     // 6400 B
    float*  ampf  = (float*)(ws + 12800);     // 3200 B
    float*  bcoef = (float*)(ws + 16000);     // 8*200*40*4 = 256000 B

    embed_kernel<<<dim3(4 * T_FRAMES), dim3(256), 0, stream>>>(
        mceps, apdcs, f0s, Wm, bm, Wa, ba, Wf, bf,
        Wpa, bpa, Wpp, bpp, Wrp, brp, Wra, bra, Wap, bcoef);

    f0_kernel<<<dim3(1), dim3(64), 0, stream>>>(f0s, based, stepd, ampf);

    mlsa_kernel<<<dim3(NCHUNK), dim3(64), 0, stream>>>(bcoef, based, stepd, ampf, noise, out);
}

// Round 4
// 1264.527 us; speedup vs baseline: 12.1393x; 1.4691x over previous
//
#include <hip/hip_runtime.h>
#include <math.h>

#define ALPHA 0.466f
#define T_FRAMES 200
#define HOPW 120
#define NSAMP 24000
#define M1 40
#define HID 256
#define CONDW 192

// time-chunking: NCHUNK chunks of CHUNKF frames; each warms up WARMF frames.
// Two chunks per wave (lanes 0-31 = chunk 2c, lanes 32-63 = chunk 2c+1).
#define NCHUNK 40
#define CHUNKF 5
#define WARMF 16
#define SERF (WARMF + CHUNKF)   // 21 frames serial per chunk

// ---------------------------------------------------------------------------
// Kernel A: frame-rate feature MLP + prenets + mc2b  -> bcoef[8][200][40]
// filters 0..3 = periodic path (b_p) for batch 0..3, 4..7 = aperiodic (b_a)
// ---------------------------------------------------------------------------
__global__ __launch_bounds__(256) void embed_kernel(
    const float* __restrict__ mceps, const float* __restrict__ apdcs,
    const float* __restrict__ f0s,
    const float* __restrict__ Wm, const float* __restrict__ bm,
    const float* __restrict__ Wa, const float* __restrict__ ba,
    const float* __restrict__ Wf, const float* __restrict__ bf,
    const float* __restrict__ Wpa, const float* __restrict__ bpa,
    const float* __restrict__ Wpp, const float* __restrict__ bpp,
    const float* __restrict__ Wrp, const float* __restrict__ brp,
    const float* __restrict__ Wra, const float* __restrict__ bra,
    const float* __restrict__ Wap, float* __restrict__ bcoef)
{
    __shared__ float s_mc[M1];
    __shared__ float s_ap[5];
    __shared__ float s_f0;
    __shared__ float s_h[HID];
    __shared__ float s_ca[CONDW];
    __shared__ float s_cp[CONDW];
    __shared__ float s_mcp[M1];
    __shared__ float s_mca[M1];

    const int bt = blockIdx.x;
    const int batch = bt / T_FRAMES;
    const int t = bt - batch * T_FRAMES;
    const int tid = threadIdx.x;

    if (tid < M1) s_mc[tid] = mceps[(batch * T_FRAMES + t) * M1 + tid];
    if (tid < 5)  s_ap[tid] = apdcs[(batch * T_FRAMES + t) * 5 + tid];
    if (tid == 0) s_f0 = f0s[batch * T_FRAMES + t];
    __syncthreads();

    {
        float acc = bm[tid] + ba[tid] + bf[tid];
        #pragma unroll 8
        for (int k = 0; k < M1; ++k) acc += s_mc[k] * Wm[k * HID + tid];
        #pragma unroll
        for (int k = 0; k < 5; ++k)  acc += s_ap[k] * Wa[k * HID + tid];
        acc += s_f0 * Wf[tid];
        s_h[tid] = acc;
    }
    __syncthreads();

    if (tid < CONDW) {
        float aA = bpa[tid];
        float aP = bpp[tid];
        #pragma unroll 8
        for (int k = 0; k < HID; ++k) {
            float h = s_h[k];
            aA += h * Wpa[k * CONDW + tid];
            aP += h * Wpp[k * CONDW + tid];
        }
        s_ca[tid] = aA;
        s_cp[tid] = aP;
    }
    __syncthreads();

    if (tid < M1) {
        float rp = brp[tid];
        float ra = bra[tid];
        #pragma unroll 8
        for (int k = 0; k < CONDW; ++k) {
            rp += s_cp[k] * Wrp[k * M1 + tid];
            ra += s_ca[k] * Wra[k * M1 + tid];
        }
        float aw = 0.f;
        #pragma unroll
        for (int k = 0; k < 5; ++k) aw += s_ap[k] * Wap[k * M1 + tid];
        s_mcp[tid] = s_mc[tid] + 0.1f * tanhf(rp);
        s_mca[tid] = s_mc[tid] + 0.1f * tanhf(ra) + aw;
    }
    __syncthreads();

    if (tid < 2) {
        const float* src = tid ? s_mca : s_mcp;
        float* dst = bcoef + ((tid * 4 + batch) * T_FRAMES + t) * M1;
        float prev = src[M1 - 1];
        dst[M1 - 1] = prev;
        for (int m = M1 - 2; m >= 0; --m) {
            prev = src[m] - ALPHA * prev;
            dst[m] = prev;
        }
    }
}

// ---------------------------------------------------------------------------
// Kernel B: per-(batch,frame) f0 -> phase base (f64 serial scan), step, amp
// ---------------------------------------------------------------------------
__global__ __launch_bounds__(64) void f0_kernel(const float* __restrict__ f0s,
    double* __restrict__ based, double* __restrict__ stepd,
    float* __restrict__ ampf)
{
    int b = threadIdx.x;
    if (b >= 4) return;
    double acc = 0.0;
    for (int ft = 0; ft < T_FRAMES; ++ft) {
        double fv = exp((double)f0s[b * T_FRAMES + ft] * 0.25 + 5.0);
        double st = fv / 24000.0;
        based[b * T_FRAMES + ft] = acc;
        stepd[b * T_FRAMES + ft] = st;
        ampf[b * T_FRAMES + ft] = (float)(0.5 * sqrt(24000.0 / fmax(fv, 1.0)));
        acc += 120.0 * st;
    }
}

// ---------------------------------------------------------------------------
// Kernel C: materialize excitation exc[8][24000] (pulse*0.5 | noise*0.5).
// Keeps all f64 math OUT of the serial scan kernel (register pressure there).
// ---------------------------------------------------------------------------
__global__ __launch_bounds__(256) void exc_kernel(
    const double* __restrict__ based, const double* __restrict__ stepd,
    const float* __restrict__ ampf, const float* __restrict__ noise,
    float* __restrict__ exc)
{
    int i = blockIdx.x * 256 + threadIdx.x;
    if (i >= 8 * NSAMP) return;
    int ff = i / NSAMP, n = i - ff * NSAMP;
    int ft = n / HOPW, k = n - ft * HOPW;
    float val;
    if (ff < 4) {
        double st = stepd[ff * T_FRAMES + ft];
        double bs = based[ff * T_FRAMES + ft];
        double ph  = bs + (double)(k + 1) * st;
        double php = bs + (double)k * st;
        val = (floor(ph) > floor(php)) ? ampf[ff * T_FRAMES + ft] : 0.0f;
    } else {
        val = 0.5f * noise[(ff - 4) * NSAMP + n];
    }
    exc[i] = val;
}

// ---------------------------------------------------------------------------
// DPP quad-perm cross-lane (VALU, ~4 cyc; replaces DS-pipe shuffles on the
// sample-to-sample carried dependency path).
// ---------------------------------------------------------------------------
template <int CTRL>
__device__ __forceinline__ float qp(float x) {
    return __int_as_float(
        __builtin_amdgcn_update_dpp(0, __float_as_int(x), CTRL, 0xF, 0xF, true));
}
// quad_perm encodings: xor1 = [1,0,3,2] = 0xB1; xor2 = [2,3,0,1] = 0x4E;
// up1-in-quad = [0,0,1,2] = 0x90.

// ---------------------------------------------------------------------------
// Kernel D: MLSA synthesis scan. Block = chunk PAIR; one wave.
// lane = half*32 + filter*4 + pade_tap; half h runs chunk 2*blockIdx.x+h.
// Warm-up frames with ft<0 run with zero excitation (state stays exactly 0).
//
// waves_per_eu(1,1): round-3 showed VGPR_Count=56 for ~95 live floats ->
// state was spilled despite __launch_bounds__(64,1). Pin occupancy to 1
// wave/EU explicitly so RA has the full 512-VGPR budget.
// ---------------------------------------------------------------------------
__global__ __launch_bounds__(64)
__attribute__((amdgpu_waves_per_eu(1, 1)))
void mlsa_kernel(
    const float* __restrict__ bcoef, const float* __restrict__ exc,
    float* __restrict__ out)
{
    __shared__ float sexc[2 * 8 * HOPW];

    const int tid = threadIdx.x;
    const int h = tid >> 5;
    const int f = (tid >> 2) & 7;
    const int p = tid & 3;

    const float AA = 1.0f - ALPHA * ALPHA;
    const float P1 = 0.4999273f, P2 = 0.1067005f, P3 = 0.00956526f, P4 = 0.0003041358f;
    const float myPade = (p == 0) ? P1 : (p == 1) ? P2 : (p == 2) ? P3 : P4;

    // ---- warped delay line d[1..40] as named scalars ----
    float d1=0.f,d2=0.f,d3=0.f,d4=0.f,d5=0.f,d6=0.f,d7=0.f,d8=0.f,d9=0.f,d10=0.f,
          d11=0.f,d12=0.f,d13=0.f,d14=0.f,d15=0.f,d16=0.f,d17=0.f,d18=0.f,d19=0.f,d20=0.f,
          d21=0.f,d22=0.f,d23=0.f,d24=0.f,d25=0.f,d26=0.f,d27=0.f,d28=0.f,d29=0.f,d30=0.f,
          d31=0.f,d32=0.f,d33=0.f,d34=0.f,d35=0.f,d36=0.f,d37=0.f,d38=0.f,d39=0.f,d40=0.f;
    // ---- stage-1 state ----
    float d1a1 = 0.f, d1a2 = 0.f, d1a3 = 0.f, d1a4 = 0.f;
    float d1b0 = 0.f, d1b1 = 0.f, d1b2 = 0.f, d1b3 = 0.f;
    float xin = 0.f;
    // ---- frame coefficients ----
    float b0,b1,b2,b3,b4,b5,b6,b7,b8,b9,b10,b11,b12,b13,b14,b15,b16,b17,b18,b19,
          b20,b21,b22,b23,b24,b25,b26,b27,b28,b29,b30,b31,b32,b33,b34,b35,b36,b37,b38,b39;

    const int chunk = blockIdx.x * 2 + h;
    const int outF0 = chunk * CHUNKF;

    #pragma unroll 1
    for (int i = 0; i < SERF; ++i) {
        const int ftA = outF0 - WARMF + i;          // this half's absolute frame

        // ---- stage both halves' excitation frames into LDS ----
        #pragma unroll 1
        for (int it = 0; it < 30; ++it) {
            int idx = tid + 64 * it;                // 0..1919
            int hh  = idx / 960;
            int rem = idx - hh * 960;
            int ffs = rem / HOPW;
            int kk  = rem - ffs * HOPW;
            int fts = (blockIdx.x * 2 + hh) * CHUNKF - WARMF + i;
            sexc[idx] = (fts >= 0) ? exc[ffs * NSAMP + fts * HOPW + kk] : 0.f;
        }
        __syncthreads();

        // ---- frame coefficients (clamped frame for warm-up; exc=0 there) ----
        {
            const int ftc = (ftA < 0) ? 0 : ftA;
            const float4* bb = (const float4*)(bcoef + (f * T_FRAMES + ftc) * M1);
            #define LD4(i_, B0,B1,B2,B3) { float4 q = bb[i_]; B0=q.x; B1=q.y; B2=q.z; B3=q.w; }
            LD4(0, b0,b1,b2,b3)   LD4(1, b4,b5,b6,b7)   LD4(2, b8,b9,b10,b11)
            LD4(3, b12,b13,b14,b15) LD4(4, b16,b17,b18,b19) LD4(5, b20,b21,b22,b23)
            LD4(6, b24,b25,b26,b27) LD4(7, b28,b29,b30,b31) LD4(8, b32,b33,b34,b35)
            LD4(9, b36,b37,b38,b39)
            #undef LD4
        }
        const float G = expf(b0);
        const bool wr = (ftA >= outF0) && (p == 0) && (f < 4);
        float* outp = out + f * NSAMP + ftA * HOPW;
        const float* sx = sexc + (h * 8 + f) * HOPW;

        // ---- sample loop ----
        for (int k = 0; k < HOPW; ++k) {
            float x = sx[k] * G;

            // stage 1 (SPTK mlsadf1), identical on the 4 tap lanes
            float na0 = AA * d1b0 + ALPHA * d1a1;
            float na1 = AA * d1b1 + ALPHA * d1a2;
            float na2 = AA * d1b2 + ALPHA * d1a3;
            float na3 = AA * d1b3 + ALPHA * d1a4;
            float n0 = na0 * b1, n1 = na1 * b1, n2 = na2 * b1, n3 = na3 * b1;
            float v10 = n0 * P1, v11 = n1 * P2, v12 = n2 * P3, v13 = n3 * P4;
            float x1 = x + ((v10 - v11) + (v12 - v13));
            float y1 = ((v10 + v11) + (v12 + v13)) + x1;
            d1a1 = na0; d1a2 = na1; d1a3 = na2; d1a4 = na3;
            d1b0 = x1;  d1b1 = n0;  d1b2 = n1;  d1b3 = n2;

            // stage 2: in-place order recurrence, rolling carry, named scalars
            float dl = AA * xin + ALPHA * d1;
            float prev = dl;
            float carry = d2;
            float fyA = 0.f, fyB = 0.f;
            #define STEPA(dn, bn) { const float nxt = dn; const float cm = fmaf(ALPHA, nxt, carry); const float tt = fmaf(-ALPHA, prev, cm); fyA = fmaf(tt, bn, fyA); dn = tt; carry = nxt; prev = tt; }
            #define STEPB(dn, bn) { const float nxt = dn; const float cm = fmaf(ALPHA, nxt, carry); const float tt = fmaf(-ALPHA, prev, cm); fyB = fmaf(tt, bn, fyB); dn = tt; carry = nxt; prev = tt; }
            STEPA(d3,b2)   STEPB(d4,b3)   STEPA(d5,b4)   STEPB(d6,b5)
            STEPA(d7,b6)   STEPB(d8,b7)   STEPA(d9,b8)   STEPB(d10,b9)
            STEPA(d11,b10) STEPB(d12,b11) STEPA(d13,b12) STEPB(d14,b13)
            STEPA(d15,b14) STEPB(d16,b15) STEPA(d17,b16) STEPB(d18,b17)
            STEPA(d19,b18) STEPB(d20,b19) STEPA(d21,b20) STEPB(d22,b21)
            STEPA(d23,b22) STEPB(d24,b23) STEPA(d25,b24) STEPB(d26,b25)
            STEPA(d27,b26) STEPB(d28,b27) STEPA(d29,b28) STEPB(d30,b29)
            STEPA(d31,b30) STEPB(d32,b31) STEPA(d33,b32) STEPB(d34,b33)
            STEPA(d35,b34) STEPB(d36,b35) STEPA(d37,b36) STEPB(d38,b37)
            STEPA(d39,b38) STEPB(d40,b39)
            #undef STEPA
            #undef STEPB
            float fy = fyA + fyB;
            d1 = dl; d2 = dl;

            // cross-tap combine via DPP quad-perms (VALU-only on carried path)
            float t2 = fy * myPade;                  // v2[p]
            float s1 = t2 + qp<0xB1>(t2);
            float Tsum = s1 + qp<0x4E>(s1);          // sum v2 (all lanes)
            float ua = t2 - qp<0xB1>(t2);
            float Usum = ua + qp<0x4E>(ua);          // sum v2*SIGN (valid on p=0)
            float x2 = y1 + Usum;
            float y2 = Tsum + x2;

            // next-sample stage-2 input: pt2' = [x2, fy0, fy1, fy2]
            float fyp = qp<0x90>(fy);                // lane p gets fy[p-1]
            xin = (p == 0) ? x2 : fyp;

            // periodic + aperiodic combine (off carried path) and store
            float yo = y2 + __shfl_xor(y2, 16);
            if (wr) outp[k] = yo;
        }
        __syncthreads();
    }
}

// ---------------------------------------------------------------------------
extern "C" void kernel_launch(void* const* d_in, const int* in_sizes, int n_in,
                              void* d_out, int out_size, void* d_ws, size_t ws_size,
                              hipStream_t stream) {
    const float* mceps = (const float*)d_in[0];
    const float* apdcs = (const float*)d_in[1];
    const float* f0s   = (const float*)d_in[2];
    const float* noise = (const float*)d_in[3];
    const float* Wm  = (const float*)d_in[4];
    const float* bm  = (const float*)d_in[5];
    const float* Wa  = (const float*)d_in[6];
    const float* ba  = (const float*)d_in[7];
    const float* Wf  = (const float*)d_in[8];
    const float* bf  = (const float*)d_in[9];
    const float* Wpa = (const float*)d_in[10];
    const float* bpa = (const float*)d_in[11];
    const float* Wpp = (const float*)d_in[12];
    const float* bpp = (const float*)d_in[13];
    const float* Wrp = (const float*)d_in[14];
    const float* brp = (const float*)d_in[15];
    const float* Wra = (const float*)d_in[16];
    const float* bra = (const float*)d_in[17];
    const float* Wap = (const float*)d_in[18];
    float* out = (float*)d_out;

    char* ws = (char*)d_ws;
    double* based = (double*)(ws + 0);         // 6400 B
    double* stepd = (double*)(ws + 6400);      // 6400 B
    float*  ampf  = (float*)(ws + 12800);      // 3200 B
    float*  bcoef = (float*)(ws + 16000);      // 256000 B
    float*  exc   = (float*)(ws + 272000);     // 8*24000*4 = 768000 B

    embed_kernel<<<dim3(4 * T_FRAMES), dim3(256), 0, stream>>>(
        mceps, apdcs, f0s, Wm, bm, Wa, ba, Wf, bf,
        Wpa, bpa, Wpp, bpp, Wrp, brp, Wra, bra, Wap, bcoef);

    f0_kernel<<<dim3(1), dim3(64), 0, stream>>>(f0s, based, stepd, ampf);

    exc_kernel<<<dim3((8 * NSAMP + 255) / 256), dim3(256), 0, stream>>>(
        based, stepd, ampf, noise, exc);

    mlsa_kernel<<<dim3(NCHUNK / 2), dim3(64), 0, stream>>>(bcoef, exc, out);
}

// Round 5
// 852.874 us; speedup vs baseline: 17.9985x; 1.4827x over previous
//
#include <hip/hip_runtime.h>
#include <math.h>

#define ALPHA 0.466f
#define T_FRAMES 200
#define HOPW 120
#define NSAMP 24000
#define M1 40
#define HID 256
#define CONDW 192

// time-chunking: NCHUNK chunks of CHUNKF frames; each warms up WARMF frames
// from zero state (filter stable; warm-up redundancy is free on an idle GPU).
// Two chunks per wave: lanes 0-31 = chunk 2c, lanes 32-63 = chunk 2c+1.
#define NCHUNK 200
#define CHUNKF 1
#define WARMF 12
#define SERF (WARMF + CHUNKF)   // 13 frames serial per chunk

#define LSTR 121                 // LDS row stride (pad 120 -> 121: bank-decorrelate)

// ---------------------------------------------------------------------------
// Kernel A: frame-rate feature MLP + prenets + mc2b  -> bcoef[8][200][40]
// filters 0..3 = periodic path (b_p) for batch 0..3, 4..7 = aperiodic (b_a)
// ---------------------------------------------------------------------------
__global__ __launch_bounds__(256) void embed_kernel(
    const float* __restrict__ mceps, const float* __restrict__ apdcs,
    const float* __restrict__ f0s,
    const float* __restrict__ Wm, const float* __restrict__ bm,
    const float* __restrict__ Wa, const float* __restrict__ ba,
    const float* __restrict__ Wf, const float* __restrict__ bf,
    const float* __restrict__ Wpa, const float* __restrict__ bpa,
    const float* __restrict__ Wpp, const float* __restrict__ bpp,
    const float* __restrict__ Wrp, const float* __restrict__ brp,
    const float* __restrict__ Wra, const float* __restrict__ bra,
    const float* __restrict__ Wap, float* __restrict__ bcoef)
{
    __shared__ float s_mc[M1];
    __shared__ float s_ap[5];
    __shared__ float s_f0;
    __shared__ float s_h[HID];
    __shared__ float s_ca[CONDW];
    __shared__ float s_cp[CONDW];
    __shared__ float s_mcp[M1];
    __shared__ float s_mca[M1];

    const int bt = blockIdx.x;
    const int batch = bt / T_FRAMES;
    const int t = bt - batch * T_FRAMES;
    const int tid = threadIdx.x;

    if (tid < M1) s_mc[tid] = mceps[(batch * T_FRAMES + t) * M1 + tid];
    if (tid < 5)  s_ap[tid] = apdcs[(batch * T_FRAMES + t) * 5 + tid];
    if (tid == 0) s_f0 = f0s[batch * T_FRAMES + t];
    __syncthreads();

    {
        float acc = bm[tid] + ba[tid] + bf[tid];
        #pragma unroll 8
        for (int k = 0; k < M1; ++k) acc += s_mc[k] * Wm[k * HID + tid];
        #pragma unroll
        for (int k = 0; k < 5; ++k)  acc += s_ap[k] * Wa[k * HID + tid];
        acc += s_f0 * Wf[tid];
        s_h[tid] = acc;
    }
    __syncthreads();

    if (tid < CONDW) {
        float aA = bpa[tid];
        float aP = bpp[tid];
        #pragma unroll 8
        for (int k = 0; k < HID; ++k) {
            float h = s_h[k];
            aA += h * Wpa[k * CONDW + tid];
            aP += h * Wpp[k * CONDW + tid];
        }
        s_ca[tid] = aA;
        s_cp[tid] = aP;
    }
    __syncthreads();

    if (tid < M1) {
        float rp = brp[tid];
        float ra = bra[tid];
        #pragma unroll 8
        for (int k = 0; k < CONDW; ++k) {
            rp += s_cp[k] * Wrp[k * M1 + tid];
            ra += s_ca[k] * Wra[k * M1 + tid];
        }
        float aw = 0.f;
        #pragma unroll
        for (int k = 0; k < 5; ++k) aw += s_ap[k] * Wap[k * M1 + tid];
        s_mcp[tid] = s_mc[tid] + 0.1f * tanhf(rp);
        s_mca[tid] = s_mc[tid] + 0.1f * tanhf(ra) + aw;
    }
    __syncthreads();

    if (tid < 2) {
        const float* src = tid ? s_mca : s_mcp;
        float* dst = bcoef + ((tid * 4 + batch) * T_FRAMES + t) * M1;
        float prev = src[M1 - 1];
        dst[M1 - 1] = prev;
        for (int m = M1 - 2; m >= 0; --m) {
            prev = src[m] - ALPHA * prev;
            dst[m] = prev;
        }
    }
}

// ---------------------------------------------------------------------------
// Kernel B: per-(batch,frame) f0 -> phase base (f64 serial scan), step, amp
// ---------------------------------------------------------------------------
__global__ __launch_bounds__(64) void f0_kernel(const float* __restrict__ f0s,
    double* __restrict__ based, double* __restrict__ stepd,
    float* __restrict__ ampf)
{
    int b = threadIdx.x;
    if (b >= 4) return;
    double acc = 0.0;
    for (int ft = 0; ft < T_FRAMES; ++ft) {
        double fv = exp((double)f0s[b * T_FRAMES + ft] * 0.25 + 5.0);
        double st = fv / 24000.0;
        based[b * T_FRAMES + ft] = acc;
        stepd[b * T_FRAMES + ft] = st;
        ampf[b * T_FRAMES + ft] = (float)(0.5 * sqrt(24000.0 / fmax(fv, 1.0)));
        acc += 120.0 * st;
    }
}

// ---------------------------------------------------------------------------
// Kernel C: materialize excitation exc[8][24000] (pulse*0.5 | noise*0.5).
// ---------------------------------------------------------------------------
__global__ __launch_bounds__(256) void exc_kernel(
    const double* __restrict__ based, const double* __restrict__ stepd,
    const float* __restrict__ ampf, const float* __restrict__ noise,
    float* __restrict__ exc)
{
    int i = blockIdx.x * 256 + threadIdx.x;
    if (i >= 8 * NSAMP) return;
    int ff = i / NSAMP, n = i - ff * NSAMP;
    int ft = n / HOPW, k = n - ft * HOPW;
    float val;
    if (ff < 4) {
        double st = stepd[ff * T_FRAMES + ft];
        double bs = based[ff * T_FRAMES + ft];
        double ph  = bs + (double)(k + 1) * st;
        double php = bs + (double)k * st;
        val = (floor(ph) > floor(php)) ? ampf[ff * T_FRAMES + ft] : 0.0f;
    } else {
        val = 0.5f * noise[(ff - 4) * NSAMP + n];
    }
    exc[i] = val;
}

// ---------------------------------------------------------------------------
// DPP quad-perm cross-lane (VALU-only; never touches the DS pipe).
// quad_perm: xor1 = [1,0,3,2] = 0xB1; xor2 = [2,3,0,1] = 0x4E;
// up1-in-quad = [0,0,1,2] = 0x90.
// ---------------------------------------------------------------------------
template <int CTRL>
__device__ __forceinline__ float qp(float x) {
    return __int_as_float(
        __builtin_amdgcn_update_dpp(0, __float_as_int(x), CTRL, 0xF, 0xF, true));
}

// ---------------------------------------------------------------------------
// Kernel D: MLSA synthesis scan. Block = chunk PAIR; one wave.
// lane = half*32 + filter*4 + pade_tap; half h runs chunk 2*blockIdx.x+h.
//
// Round-4 model: per-sample cost = VALU issue (~330cyc) + TWO serialized DS
// round-trips (sexc ds_read at top, ds_bpermute+waitcnt tail for the P+A
// combine). This version: (1) software-pipelines the sexc read (prefetch
// k+1, consume k) so the 120cyc ds_read hides under the body; (2) defers
// the P+A combine: p==0 lanes ds_write y2 (fire-and-forget, no in-loop
// waitcnt), cooperative combine+store after the sample loop.
// ---------------------------------------------------------------------------
__global__ __launch_bounds__(64)
__attribute__((amdgpu_waves_per_eu(1, 1)))
void mlsa_kernel(
    const float* __restrict__ bcoef, const float* __restrict__ exc,
    float* __restrict__ out)
{
    __shared__ float sexc[16 * LSTR];    // [h*8+f][k], stride-padded
    __shared__ float y2buf[16 * LSTR];   // [h*8+f][k], stride-padded

    const int tid = threadIdx.x;
    const int h = tid >> 5;
    const int f = (tid >> 2) & 7;
    const int p = tid & 3;

    const float AA = 1.0f - ALPHA * ALPHA;
    const float P1 = 0.4999273f, P2 = 0.1067005f, P3 = 0.00956526f, P4 = 0.0003041358f;
    const float myPade = (p == 0) ? P1 : (p == 1) ? P2 : (p == 2) ? P3 : P4;

    // ---- warped delay line d[1..40] as named scalars ----
    float d1=0.f,d2=0.f,d3=0.f,d4=0.f,d5=0.f,d6=0.f,d7=0.f,d8=0.f,d9=0.f,d10=0.f,
          d11=0.f,d12=0.f,d13=0.f,d14=0.f,d15=0.f,d16=0.f,d17=0.f,d18=0.f,d19=0.f,d20=0.f,
          d21=0.f,d22=0.f,d23=0.f,d24=0.f,d25=0.f,d26=0.f,d27=0.f,d28=0.f,d29=0.f,d30=0.f,
          d31=0.f,d32=0.f,d33=0.f,d34=0.f,d35=0.f,d36=0.f,d37=0.f,d38=0.f,d39=0.f,d40=0.f;
    // ---- stage-1 state ----
    float d1a1 = 0.f, d1a2 = 0.f, d1a3 = 0.f, d1a4 = 0.f;
    float d1b0 = 0.f, d1b1 = 0.f, d1b2 = 0.f, d1b3 = 0.f;
    float xin = 0.f;
    // ---- frame coefficients ----
    float b0,b1,b2,b3,b4,b5,b6,b7,b8,b9,b10,b11,b12,b13,b14,b15,b16,b17,b18,b19,
          b20,b21,b22,b23,b24,b25,b26,b27,b28,b29,b30,b31,b32,b33,b34,b35,b36,b37,b38,b39;

    const int chunk = blockIdx.x * 2 + h;
    const int outF0 = chunk * CHUNKF;

    const float* sx = sexc + (h * 8 + f) * LSTR;
    float* y2p = y2buf + (h * 8 + f) * LSTR;

    #pragma unroll 1
    for (int i = 0; i < SERF; ++i) {
        const int ftA = outF0 - WARMF + i;          // this half's absolute frame

        // ---- stage both halves' excitation frames into LDS ----
        #pragma unroll 1
        for (int it = 0; it < 30; ++it) {
            int idx = tid + 64 * it;                // 0..1919
            int hf = idx / HOPW;                    // 0..15
            int kk = idx - hf * HOPW;
            int hh = hf >> 3;
            int ff = hf & 7;
            int fts = (blockIdx.x * 2 + hh) * CHUNKF - WARMF + i;
            sexc[hf * LSTR + kk] = (fts >= 0) ? exc[ff * NSAMP + fts * HOPW + kk] : 0.f;
        }
        __syncthreads();

        // ---- frame coefficients (clamped frame for warm-up; exc=0 there) ----
        {
            const int ftc = (ftA < 0) ? 0 : ftA;
            const float4* bb = (const float4*)(bcoef + (f * T_FRAMES + ftc) * M1);
            #define LD4(i_, B0,B1,B2,B3) { float4 q = bb[i_]; B0=q.x; B1=q.y; B2=q.z; B3=q.w; }
            LD4(0, b0,b1,b2,b3)   LD4(1, b4,b5,b6,b7)   LD4(2, b8,b9,b10,b11)
            LD4(3, b12,b13,b14,b15) LD4(4, b16,b17,b18,b19) LD4(5, b20,b21,b22,b23)
            LD4(6, b24,b25,b26,b27) LD4(7, b28,b29,b30,b31) LD4(8, b32,b33,b34,b35)
            LD4(9, b36,b37,b38,b39)
            #undef LD4
        }
        const float G = expf(b0);

        // ---- sample loop (prefetched excitation; no in-loop waitcnt tail) ----
        float xc = sx[0];
        for (int k = 0; k < HOPW; ++k) {
            float xn = sx[k + 1];                   // prefetch (row is LSTR-padded)
            float x = xc * G;

            // stage 1 (SPTK mlsadf1), identical on the 4 tap lanes
            float na0 = AA * d1b0 + ALPHA * d1a1;
            float na1 = AA * d1b1 + ALPHA * d1a2;
            float na2 = AA * d1b2 + ALPHA * d1a3;
            float na3 = AA * d1b3 + ALPHA * d1a4;
            float n0 = na0 * b1, n1 = na1 * b1, n2 = na2 * b1, n3 = na3 * b1;
            float v10 = n0 * P1, v11 = n1 * P2, v12 = n2 * P3, v13 = n3 * P4;
            float x1 = x + ((v10 - v11) + (v12 - v13));
            float y1 = ((v10 + v11) + (v12 + v13)) + x1;
            d1a1 = na0; d1a2 = na1; d1a3 = na2; d1a4 = na3;
            d1b0 = x1;  d1b1 = n0;  d1b2 = n1;  d1b3 = n2;

            // stage 2: in-place order recurrence, rolling carry, named scalars
            float dl = AA * xin + ALPHA * d1;
            float prev = dl;
            float carry = d2;
            float fyA = 0.f, fyB = 0.f;
            #define STEPA(dn, bn) { const float nxt = dn; const float cm = fmaf(ALPHA, nxt, carry); const float tt = fmaf(-ALPHA, prev, cm); fyA = fmaf(tt, bn, fyA); dn = tt; carry = nxt; prev = tt; }
            #define STEPB(dn, bn) { const float nxt = dn; const float cm = fmaf(ALPHA, nxt, carry); const float tt = fmaf(-ALPHA, prev, cm); fyB = fmaf(tt, bn, fyB); dn = tt; carry = nxt; prev = tt; }
            STEPA(d3,b2)   STEPB(d4,b3)   STEPA(d5,b4)   STEPB(d6,b5)
            STEPA(d7,b6)   STEPB(d8,b7)   STEPA(d9,b8)   STEPB(d10,b9)
            STEPA(d11,b10) STEPB(d12,b11) STEPA(d13,b12) STEPB(d14,b13)
            STEPA(d15,b14) STEPB(d16,b15) STEPA(d17,b16) STEPB(d18,b17)
            STEPA(d19,b18) STEPB(d20,b19) STEPA(d21,b20) STEPB(d22,b21)
            STEPA(d23,b22) STEPB(d24,b23) STEPA(d25,b24) STEPB(d26,b25)
            STEPA(d27,b26) STEPB(d28,b27) STEPA(d29,b28) STEPB(d30,b29)
            STEPA(d31,b30) STEPB(d32,b31) STEPA(d33,b32) STEPB(d34,b33)
            STEPA(d35,b34) STEPB(d36,b35) STEPA(d37,b36) STEPB(d38,b37)
            STEPA(d39,b38) STEPB(d40,b39)
            #undef STEPA
            #undef STEPB
            float fy = fyA + fyB;
            d1 = dl; d2 = dl;

            // cross-tap combine via DPP quad-perms (VALU-only)
            float t2 = fy * myPade;                  // v2[p]
            float s1 = t2 + qp<0xB1>(t2);
            float Tsum = s1 + qp<0x4E>(s1);          // sum v2 (all lanes)
            float ua = t2 - qp<0xB1>(t2);
            float Usum = ua + qp<0x4E>(ua);          // sum v2*SIGN (valid on p=0)
            float x2 = y1 + Usum;
            float y2 = Tsum + x2;

            // next-sample stage-2 input: pt2' = [x2, fy0, fy1, fy2]
            float fyp = qp<0x90>(fy);                // lane p gets fy[p-1]
            xin = (p == 0) ? x2 : fyp;

            // stash y2 (p==0 lanes); ds_write is fire-and-forget
            if (p == 0) y2p[k] = y2;
            xc = xn;
        }
        __syncthreads();

        // ---- P+A combine + global store (off the serial path) ----
        if (i >= WARMF) {
            #pragma unroll 1
            for (int it = 0; it < 15; ++it) {
                int j = tid + 64 * it;               // 0..959
                int hh = j / 480;
                int rem = j - hh * 480;
                int bb = rem / HOPW;
                int kk = rem - bb * HOPW;
                float v = y2buf[(hh * 8 + bb) * LSTR + kk]
                        + y2buf[(hh * 8 + 4 + bb) * LSTR + kk];
                int ftO = (blockIdx.x * 2 + hh) * CHUNKF + (i - WARMF);
                out[bb * NSAMP + ftO * HOPW + kk] = v;
            }
        }
    }
}

// ---------------------------------------------------------------------------
extern "C" void kernel_launch(void* const* d_in, const int* in_sizes, int n_in,
                              void* d_out, int out_size, void* d_ws, size_t ws_size,
                              hipStream_t stream) {
    const float* mceps = (const float*)d_in[0];
    const float* apdcs = (const float*)d_in[1];
    const float* f0s   = (const float*)d_in[2];
    const float* noise = (const float*)d_in[3];
    const float* Wm  = (const float*)d_in[4];
    const float* bm  = (const float*)d_in[5];
    const float* Wa  = (const float*)d_in[6];
    const float* ba  = (const float*)d_in[7];
    const float* Wf  = (const float*)d_in[8];
    const float* bf  = (const float*)d_in[9];
    const float* Wpa = (const float*)d_in[10];
    const float* bpa = (const float*)d_in[11];
    const float* Wpp = (const float*)d_in[12];
    const float* bpp = (const float*)d_in[13];
    const float* Wrp = (const float*)d_in[14];
    const float* brp = (const float*)d_in[15];
    const float* Wra = (const float*)d_in[16];
    const float* bra = (const float*)d_in[17];
    const float* Wap = (const float*)d_in[18];
    float* out = (float*)d_out;

    char* ws = (char*)d_ws;
    double* based = (double*)(ws + 0);         // 6400 B
    double* stepd = (double*)(ws + 6400);      // 6400 B
    float*  ampf  = (float*)(ws + 12800);      // 3200 B
    float*  bcoef = (float*)(ws + 16000);      // 256000 B
    float*  exc   = (float*)(ws + 272000);     // 8*24000*4 = 768000 B

    embed_kernel<<<dim3(4 * T_FRAMES), dim3(256), 0, stream>>>(
        mceps, apdcs, f0s, Wm, bm, Wa, ba, Wf, bf,
        Wpa, bpa, Wpp, bpp, Wrp, brp, Wra, bra, Wap, bcoef);

    f0_kernel<<<dim3(1), dim3(64), 0, stream>>>(f0s, based, stepd, ampf);

    exc_kernel<<<dim3((8 * NSAMP + 255) / 256), dim3(256), 0, stream>>>(
        based, stepd, ampf, noise, exc);

    mlsa_kernel<<<dim3(NCHUNK / 2), dim3(64), 0, stream>>>(bcoef, exc, out);
}

// Round 6
// 587.582 us; speedup vs baseline: 26.1248x; 1.4515x over previous
//
#include <hip/hip_runtime.h>
#include <math.h>

#define ALPHA 0.466f
#define T_FRAMES 200
#define HOPW 120
#define NSAMP 24000
#define M1 40
#define HID 256
#define CONDW 192

// time-chunking: one chunk = one output frame; warm up WARMF frames from
// zero state (filter stable). One WAVE per (chunk, filter): 200*8 = 1600.
#define NCHUNK 200
#define CHUNKF 1
#define WARMF 12
#define SERF (WARMF + CHUNKF)   // 13 frames serial per chunk

// ---------------------------------------------------------------------------
// Kernel A: frame-rate feature MLP + prenets + mc2b  -> bcoef[8][200][40]
// filters 0..3 = periodic path (b_p) for batch 0..3, 4..7 = aperiodic (b_a)
// ---------------------------------------------------------------------------
__global__ __launch_bounds__(256) void embed_kernel(
    const float* __restrict__ mceps, const float* __restrict__ apdcs,
    const float* __restrict__ f0s,
    const float* __restrict__ Wm, const float* __restrict__ bm,
    const float* __restrict__ Wa, const float* __restrict__ ba,
    const float* __restrict__ Wf, const float* __restrict__ bf,
    const float* __restrict__ Wpa, const float* __restrict__ bpa,
    const float* __restrict__ Wpp, const float* __restrict__ bpp,
    const float* __restrict__ Wrp, const float* __restrict__ brp,
    const float* __restrict__ Wra, const float* __restrict__ bra,
    const float* __restrict__ Wap, float* __restrict__ bcoef)
{
    __shared__ float s_mc[M1];
    __shared__ float s_ap[5];
    __shared__ float s_f0;
    __shared__ float s_h[HID];
    __shared__ float s_ca[CONDW];
    __shared__ float s_cp[CONDW];
    __shared__ float s_mcp[M1];
    __shared__ float s_mca[M1];

    const int bt = blockIdx.x;
    const int batch = bt / T_FRAMES;
    const int t = bt - batch * T_FRAMES;
    const int tid = threadIdx.x;

    if (tid < M1) s_mc[tid] = mceps[(batch * T_FRAMES + t) * M1 + tid];
    if (tid < 5)  s_ap[tid] = apdcs[(batch * T_FRAMES + t) * 5 + tid];
    if (tid == 0) s_f0 = f0s[batch * T_FRAMES + t];
    __syncthreads();

    {
        float acc = bm[tid] + ba[tid] + bf[tid];
        #pragma unroll 8
        for (int k = 0; k < M1; ++k) acc += s_mc[k] * Wm[k * HID + tid];
        #pragma unroll
        for (int k = 0; k < 5; ++k)  acc += s_ap[k] * Wa[k * HID + tid];
        acc += s_f0 * Wf[tid];
        s_h[tid] = acc;
    }
    __syncthreads();

    if (tid < CONDW) {
        float aA = bpa[tid];
        float aP = bpp[tid];
        #pragma unroll 8
        for (int k = 0; k < HID; ++k) {
            float h = s_h[k];
            aA += h * Wpa[k * CONDW + tid];
            aP += h * Wpp[k * CONDW + tid];
        }
        s_ca[tid] = aA;
        s_cp[tid] = aP;
    }
    __syncthreads();

    if (tid < M1) {
        float rp = brp[tid];
        float ra = bra[tid];
        #pragma unroll 8
        for (int k = 0; k < CONDW; ++k) {
            rp += s_cp[k] * Wrp[k * M1 + tid];
            ra += s_ca[k] * Wra[k * M1 + tid];
        }
        float aw = 0.f;
        #pragma unroll
        for (int k = 0; k < 5; ++k) aw += s_ap[k] * Wap[k * M1 + tid];
        s_mcp[tid] = s_mc[tid] + 0.1f * tanhf(rp);
        s_mca[tid] = s_mc[tid] + 0.1f * tanhf(ra) + aw;
    }
    __syncthreads();

    if (tid < 2) {
        const float* src = tid ? s_mca : s_mcp;
        float* dst = bcoef + ((tid * 4 + batch) * T_FRAMES + t) * M1;
        float prev = src[M1 - 1];
        dst[M1 - 1] = prev;
        for (int m = M1 - 2; m >= 0; --m) {
            prev = src[m] - ALPHA * prev;
            dst[m] = prev;
        }
    }
}

// ---------------------------------------------------------------------------
// Kernel B: per-(batch,frame) f0 -> phase base (f64 serial scan), step, amp
// ---------------------------------------------------------------------------
__global__ __launch_bounds__(64) void f0_kernel(const float* __restrict__ f0s,
    double* __restrict__ based, double* __restrict__ stepd,
    float* __restrict__ ampf)
{
    int b = threadIdx.x;
    if (b >= 4) return;
    double acc = 0.0;
    for (int ft = 0; ft < T_FRAMES; ++ft) {
        double fv = exp((double)f0s[b * T_FRAMES + ft] * 0.25 + 5.0);
        double st = fv / 24000.0;
        based[b * T_FRAMES + ft] = acc;
        stepd[b * T_FRAMES + ft] = st;
        ampf[b * T_FRAMES + ft] = (float)(0.5 * sqrt(24000.0 / fmax(fv, 1.0)));
        acc += 120.0 * st;
    }
}

// ---------------------------------------------------------------------------
// Kernel C: materialize excitation exc[8][24000] (pulse*0.5 | noise*0.5).
// ---------------------------------------------------------------------------
__global__ __launch_bounds__(256) void exc_kernel(
    const double* __restrict__ based, const double* __restrict__ stepd,
    const float* __restrict__ ampf, const float* __restrict__ noise,
    float* __restrict__ exc)
{
    int i = blockIdx.x * 256 + threadIdx.x;
    if (i >= 8 * NSAMP) return;
    int ff = i / NSAMP, n = i - ff * NSAMP;
    int ft = n / HOPW, k = n - ft * HOPW;
    float val;
    if (ff < 4) {
        double st = stepd[ff * T_FRAMES + ft];
        double bs = based[ff * T_FRAMES + ft];
        double ph  = bs + (double)(k + 1) * st;
        double php = bs + (double)k * st;
        val = (floor(ph) > floor(php)) ? ampf[ff * T_FRAMES + ft] : 0.0f;
    } else {
        val = 0.5f * noise[(ff - 4) * NSAMP + n];
    }
    exc[i] = val;
}

// ---------------------------------------------------------------------------
// DPP helpers (VALU-only cross-lane). row_shr:N = 0x110|N (within 16-lane row,
// bound_ctrl=true -> shifted-in lanes read 0 == exact scan boundary semantics).
// ---------------------------------------------------------------------------
template <int CTRL>
__device__ __forceinline__ float dppf(float x) {
    return __int_as_float(
        __builtin_amdgcn_update_dpp(0, __float_as_int(x), CTRL, 0xF, 0xF, true));
}
__device__ __forceinline__ float rlane(float x, int l) {
    return __int_as_float(__builtin_amdgcn_readlane(__float_as_int(x), l));
}

// ---------------------------------------------------------------------------
// Kernel D: MLSA synthesis scan, lane-parallel.
// Wave = one (chunk, filter). Lane = tap*16 + i; 16-lane row = one Pade tap.
// Lane i owns delay-line recurrence indices m in {3i,3i+1,3i+2} (m=0..37 real,
// rest padded with b=0 -> flows forward only, harmless).
//
// Recurrence tt_m = c_m - a*tt_{m-1} is linear -> blocked affine scan:
//   local: u_a=c_a, u_b=c_b-a*u_a, u_c=c_c-a*u_b
//   Kogge-Stone over u_c with ratio r=(-a)^3 (4 DPP row_shr levels)
//   seed: true tt_{3i+2} = X_i + r^{i+1}*dl ; S_in = row_shr1, lane0 <- dl
//   t_a = u_a - a*S_in ; t_b = u_b + a^2*S_in
// fy = row-sum(t_a*Ba + t_b*Bb + t_c*Bc) via DPP prefix + readlane(15/31/47/63).
// Cross-tap glue done redundantly in all lanes from the 4 broadcast fy's.
// ZERO DS/global ops on the carried path (exc prefetched; y2 store only in
// the single output frame, fire-and-forget).
// ---------------------------------------------------------------------------
__global__ __launch_bounds__(64) void mlsa_kernel(
    const float* __restrict__ bcoef, const float* __restrict__ exc,
    float* __restrict__ y2g)
{
    __shared__ float sexc[HOPW + 2];

    const int tid = threadIdx.x;
    const int i16 = tid & 15;            // position in row
    const int row = tid >> 4;            // Pade tap p
    const int chunk = blockIdx.x >> 3;
    const int f = blockIdx.x & 7;

    const float A = ALPHA;
    const float AA = 1.0f - A * A;
    const float A2 = A * A;
    const float R1 = -(A * A * A);       // (-a)^3
    const float R2 = R1 * R1;
    const float R4 = R2 * R2;
    const float R8 = R4 * R4;
    const float P1 = 0.4999273f, P2 = 0.1067005f, P3 = 0.00956526f, P4 = 0.0003041358f;

    // per-lane seed constant K = r^(i+1)
    float K = R1;
    for (int j = 0; j < i16; ++j) K *= R1;

    // ---- state ----
    float E0 = 0.f, E1 = 0.f, E2 = 0.f;          // delay line d[3i+3..3i+5]
    float dlp = 0.f;                              // dl of previous sample (= d1 = d2)
    float xin = 0.f;                              // pt2 input for this tap
    float d1a1 = 0.f, d1a2 = 0.f, d1a3 = 0.f, d1a4 = 0.f;   // stage-1
    float d1b0 = 0.f, d1b1 = 0.f, d1b2 = 0.f, d1b3 = 0.f;

    const int outF0 = chunk * CHUNKF;

    #pragma unroll 1
    for (int i = 0; i < SERF; ++i) {
        const int ftA = outF0 - WARMF + i;

        // ---- stage excitation for this filter/frame ----
        for (int j = tid; j < HOPW; j += 64)
            sexc[j] = (ftA >= 0) ? exc[f * NSAMP + ftA * HOPW + j] : 0.f;
        if (tid == 0) sexc[HOPW] = 0.f;
        __syncthreads();

        // ---- frame coefficients ----
        const int ftc = (ftA < 0) ? 0 : ftA;
        const float* bp = bcoef + (f * T_FRAMES + ftc) * M1;
        const float b1 = bp[1];
        const float G  = expf(bp[0]);
        const int ja = 3 * i16 + 2;
        const float Ba = (i16 <= 12) ? bp[ja]     : 0.f;   // b[m+2], m=3i
        const float Bb = (i16 <= 12) ? bp[ja + 1] : 0.f;   // m=3i+1
        const float Bc = (i16 <= 11) ? bp[ja + 2] : 0.f;   // m=3i+2
        const bool isOut = (i == WARMF);
        float* yout = y2g + f * NSAMP + ftA * HOPW;

        // ---- sample loop ----
        float xc = sexc[0];
        for (int k = 0; k < HOPW; ++k) {
            float xn = sexc[k + 1];
            float x = xc * G;

            // stage 1 (SPTK mlsadf1), identical in all 64 lanes
            float na0 = AA * d1b0 + A * d1a1;
            float na1 = AA * d1b1 + A * d1a2;
            float na2 = AA * d1b2 + A * d1a3;
            float na3 = AA * d1b3 + A * d1a4;
            float n0 = na0 * b1, n1 = na1 * b1, n2 = na2 * b1, n3 = na3 * b1;
            float v10 = n0 * P1, v11 = n1 * P2, v12 = n2 * P3, v13 = n3 * P4;
            float x1 = x + ((v10 - v11) + (v12 - v13));
            float y1 = ((v10 + v11) + (v12 + v13)) + x1;
            d1a1 = na0; d1a2 = na1; d1a3 = na2; d1a4 = na3;
            d1b0 = x1;  d1b1 = n0;  d1b2 = n1;  d1b3 = n2;

            // ---- stage 2: blocked affine scan over the order recurrence ----
            float pE2 = dppf<0x111>(E2);                  // neighbor's old E2
            float ca = fmaf(A, E0, (i16 == 0) ? dlp : pE2);
            float cb = fmaf(A, E1, E0);
            float cc = fmaf(A, E2, E1);
            float ua = ca;
            float ub = fmaf(-A, ua, cb);
            float uc = fmaf(-A, ub, cc);
            float X = uc;
            X = fmaf(R1, dppf<0x111>(X), X);
            X = fmaf(R2, dppf<0x112>(X), X);
            X = fmaf(R4, dppf<0x114>(X), X);
            X = fmaf(R8, dppf<0x118>(X), X);
            float dl = fmaf(AA, xin, A * dlp);
            float Xt = fmaf(K, dl, X);                    // true tt_{3i+2}
            float Si = dppf<0x111>(Xt);
            Si = (i16 == 0) ? dl : Si;                    // true tt_{3i-1}
            float ta = fmaf(-A, Si, ua);                  // tt_{3i}
            float tb = fmaf(A2, Si, ub);                  // tt_{3i+1}

            // fy partial + row reduction (prefix sum; total lands in lane 15)
            float fp = ta * Ba;
            fp = fmaf(tb, Bb, fp);
            fp = fmaf(Xt, Bc, fp);
            float S = fp;
            S += dppf<0x111>(S);
            S += dppf<0x112>(S);
            S += dppf<0x114>(S);
            S += dppf<0x118>(S);
            float fy0 = rlane(S, 15);
            float fy1 = rlane(S, 31);
            float fy2 = rlane(S, 47);
            float fy3 = rlane(S, 63);

            // cross-tap glue (redundant in all lanes)
            float v20 = fy0 * P1, v21 = fy1 * P2, v22 = fy2 * P3, v23 = fy3 * P4;
            float Tsum = (v20 + v21) + (v22 + v23);
            float Usum = (v20 - v21) + (v22 - v23);
            float x2 = y1 + Usum;
            float y2 = Tsum + x2;

            // next-sample inputs
            xin = (row == 0) ? x2 : (row == 1) ? fy0 : (row == 2) ? fy1 : fy2;
            E0 = ta; E1 = tb; E2 = Xt;
            dlp = dl;

            if (isOut) {
                if (tid == 0) yout[k] = y2;
            }
            xc = xn;
        }
        __syncthreads();
    }
}

// ---------------------------------------------------------------------------
// Kernel E: out[b][n] = y2g[b][n] + y2g[4+b][n]
// ---------------------------------------------------------------------------
__global__ __launch_bounds__(256) void combine_kernel(
    const float* __restrict__ y2g, float* __restrict__ out)
{
    int i = blockIdx.x * 256 + threadIdx.x;
    if (i >= 4 * NSAMP) return;
    int b = i / NSAMP, n = i - b * NSAMP;
    out[i] = y2g[b * NSAMP + n] + y2g[(4 + b) * NSAMP + n];
}

// ---------------------------------------------------------------------------
extern "C" void kernel_launch(void* const* d_in, const int* in_sizes, int n_in,
                              void* d_out, int out_size, void* d_ws, size_t ws_size,
                              hipStream_t stream) {
    const float* mceps = (const float*)d_in[0];
    const float* apdcs = (const float*)d_in[1];
    const float* f0s   = (const float*)d_in[2];
    const float* noise = (const float*)d_in[3];
    const float* Wm  = (const float*)d_in[4];
    const float* bm  = (const float*)d_in[5];
    const float* Wa  = (const float*)d_in[6];
    const float* ba  = (const float*)d_in[7];
    const float* Wf  = (const float*)d_in[8];
    const float* bf  = (const float*)d_in[9];
    const float* Wpa = (const float*)d_in[10];
    const float* bpa = (const float*)d_in[11];
    const float* Wpp = (const float*)d_in[12];
    const float* bpp = (const float*)d_in[13];
    const float* Wrp = (const float*)d_in[14];
    const float* brp = (const float*)d_in[15];
    const float* Wra = (const float*)d_in[16];
    const float* bra = (const float*)d_in[17];
    const float* Wap = (const float*)d_in[18];
    float* out = (float*)d_out;

    char* ws = (char*)d_ws;
    double* based = (double*)(ws + 0);          // 6400 B
    double* stepd = (double*)(ws + 6400);       // 6400 B
    float*  ampf  = (float*)(ws + 12800);       // 3200 B
    float*  bcoef = (float*)(ws + 16000);       // 256000 B
    float*  exc   = (float*)(ws + 272000);      // 768000 B
    float*  y2g   = (float*)(ws + 1040000);     // 768000 B  (total 1.81 MB)

    embed_kernel<<<dim3(4 * T_FRAMES), dim3(256), 0, stream>>>(
        mceps, apdcs, f0s, Wm, bm, Wa, ba, Wf, bf,
        Wpa, bpa, Wpp, bpp, Wrp, brp, Wra, bra, Wap, bcoef);

    f0_kernel<<<dim3(1), dim3(64), 0, stream>>>(f0s, based, stepd, ampf);

    exc_kernel<<<dim3((8 * NSAMP + 255) / 256), dim3(256), 0, stream>>>(
        based, stepd, ampf, noise, exc);

    mlsa_kernel<<<dim3(NCHUNK * 8), dim3(64), 0, stream>>>(bcoef, exc, y2g);

    combine_kernel<<<dim3((4 * NSAMP + 255) / 256), dim3(256), 0, stream>>>(
        y2g, out);
}

// Round 7
// 408.587 us; speedup vs baseline: 37.5697x; 1.4381x over previous
//
#include <hip/hip_runtime.h>
#include <math.h>

#define ALPHA 0.466f
#define T_FRAMES 200
#define HOPW 120
#define NSAMP 24000
#define M1 40
#define HID 256
#define CONDW 192

// time-chunking: NCHUNK chunks of CHUNKF output frames, WARMF warm-up frames
// from zero state. One WAVE per (chunk, filter): 100*8 = 800 waves <= 1024
// SIMDs -> at most 1 wave/SIMD (round-6 straggler fix).
#define NCHUNK 100
#define CHUNKF 2
#define WARMF 8
#define SERF (WARMF + CHUNKF)   // 10 frames serial per chunk

#define F8 8                     // frames per embed block

// ---------------------------------------------------------------------------
// Kernel A: frame-rate feature MLP + prenets + mc2b  -> bcoef[8][200][40]
// 100 blocks x 8 frames: weights are read once per block (round-6: one block
// per frame re-read Wpa/Wpp 800x = ~300 MB of L2 traffic ~= 100 us).
// ---------------------------------------------------------------------------
__global__ __launch_bounds__(256) void embed_kernel(
    const float* __restrict__ mceps, const float* __restrict__ apdcs,
    const float* __restrict__ f0s,
    const float* __restrict__ Wm, const float* __restrict__ bm,
    const float* __restrict__ Wa, const float* __restrict__ ba,
    const float* __restrict__ Wf, const float* __restrict__ bf,
    const float* __restrict__ Wpa, const float* __restrict__ bpa,
    const float* __restrict__ Wpp, const float* __restrict__ bpp,
    const float* __restrict__ Wrp, const float* __restrict__ brp,
    const float* __restrict__ Wra, const float* __restrict__ bra,
    const float* __restrict__ Wap, float* __restrict__ bcoef)
{
    __shared__ float s_mc[F8][M1];
    __shared__ float s_ap[F8][5];
    __shared__ float s_f0[F8];
    __shared__ float s_h[F8][HID];
    __shared__ float s_ca[F8][CONDW];
    __shared__ float s_cp[F8][CONDW];
    __shared__ float s_mcp[F8][M1];
    __shared__ float s_mca[F8][M1];

    const int tid = threadIdx.x;
    const int R0 = blockIdx.x * F8;   // first global row (= batch*T + t; F8 | T)

    // ---- stage inputs (rows are contiguous) ----
    for (int j = tid; j < F8 * M1; j += 256) s_mc[j / M1][j % M1] = mceps[R0 * M1 + j];
    if (tid < F8 * 5) s_ap[tid / 5][tid % 5] = apdcs[R0 * 5 + tid];
    if (tid < F8)     s_f0[tid] = f0s[R0 + tid];
    __syncthreads();

    // ---- phase 1: h = mc@Wm + ap@Wa + f0@Wf + biases  (thread = hid unit) ----
    {
        float acc[F8];
        const float bias = bm[tid] + ba[tid] + bf[tid];
        #pragma unroll
        for (int r = 0; r < F8; ++r) acc[r] = bias;
        for (int k = 0; k < M1; ++k) {
            float w = Wm[k * HID + tid];
            #pragma unroll
            for (int r = 0; r < F8; ++r) acc[r] = fmaf(s_mc[r][k], w, acc[r]);
        }
        #pragma unroll
        for (int k = 0; k < 5; ++k) {
            float w = Wa[k * HID + tid];
            #pragma unroll
            for (int r = 0; r < F8; ++r) acc[r] = fmaf(s_ap[r][k], w, acc[r]);
        }
        float wf = Wf[tid];
        #pragma unroll
        for (int r = 0; r < F8; ++r) s_h[r][tid] = fmaf(s_f0[r], wf, acc[r]);
    }
    __syncthreads();

    // ---- phase 2: ca = h@Wpa + bpa, cp = h@Wpp + bpp  (thread = cond unit) ----
    if (tid < CONDW) {
        float aA[F8], aP[F8];
        #pragma unroll
        for (int r = 0; r < F8; ++r) { aA[r] = bpa[tid]; aP[r] = bpp[tid]; }
        for (int k = 0; k < HID; k += 4) {
            float4 h4[F8];
            #pragma unroll
            for (int r = 0; r < F8; ++r) h4[r] = *(const float4*)&s_h[r][k];
            #pragma unroll
            for (int kk = 0; kk < 4; ++kk) {
                float wa = Wpa[(k + kk) * CONDW + tid];
                float wp = Wpp[(k + kk) * CONDW + tid];
                #pragma unroll
                for (int r = 0; r < F8; ++r) {
                    float hv = (&h4[r].x)[kk];
                    aA[r] = fmaf(hv, wa, aA[r]);
                    aP[r] = fmaf(hv, wp, aP[r]);
                }
            }
        }
        #pragma unroll
        for (int r = 0; r < F8; ++r) { s_ca[r][tid] = aA[r]; s_cp[r][tid] = aP[r]; }
    }
    __syncthreads();

    // ---- phase 3: prenet residuals (wave0: path p; wave1: path a) ----
    if (tid < M1) {
        const int u = tid;
        float acc[F8];
        #pragma unroll
        for (int r = 0; r < F8; ++r) acc[r] = brp[u];
        for (int k = 0; k < CONDW; k += 4) {
            float4 c4[F8];
            #pragma unroll
            for (int r = 0; r < F8; ++r) c4[r] = *(const float4*)&s_cp[r][k];
            #pragma unroll
            for (int kk = 0; kk < 4; ++kk) {
                float w = Wrp[(k + kk) * M1 + u];
                #pragma unroll
                for (int r = 0; r < F8; ++r) acc[r] = fmaf((&c4[r].x)[kk], w, acc[r]);
            }
        }
        #pragma unroll
        for (int r = 0; r < F8; ++r)
            s_mcp[r][u] = s_mc[r][u] + 0.1f * tanhf(acc[r]);
    } else if (tid >= 64 && tid < 64 + M1) {
        const int u = tid - 64;
        float acc[F8];
        #pragma unroll
        for (int r = 0; r < F8; ++r) acc[r] = bra[u];
        for (int k = 0; k < CONDW; k += 4) {
            float4 c4[F8];
            #pragma unroll
            for (int r = 0; r < F8; ++r) c4[r] = *(const float4*)&s_ca[r][k];
            #pragma unroll
            for (int kk = 0; kk < 4; ++kk) {
                float w = Wra[(k + kk) * M1 + u];
                #pragma unroll
                for (int r = 0; r < F8; ++r) acc[r] = fmaf((&c4[r].x)[kk], w, acc[r]);
            }
        }
        #pragma unroll
        for (int r = 0; r < F8; ++r) {
            float aw = 0.f;
            #pragma unroll
            for (int j = 0; j < 5; ++j) aw = fmaf(s_ap[r][j], Wap[j * M1 + u], aw);
            s_mca[r][u] = s_mc[r][u] + 0.1f * tanhf(acc[r]) + aw;
        }
    }
    __syncthreads();

    // ---- phase 4: mc2b (serial order-40 scan), 16 threads ----
    if (tid < 16) {
        const int r = tid >> 1, path = tid & 1;
        const int R = R0 + r;
        const int batch = R / T_FRAMES, t = R - batch * T_FRAMES;
        const float* src = path ? s_mca[r] : s_mcp[r];
        float* dst = bcoef + ((path * 4 + batch) * T_FRAMES + t) * M1;
        float prev = src[M1 - 1];
        dst[M1 - 1] = prev;
        for (int m = M1 - 2; m >= 0; --m) {
            prev = src[m] - ALPHA * prev;
            dst[m] = prev;
        }
    }
}

// ---------------------------------------------------------------------------
// Kernel B: per-(batch,frame) f0 -> phase base (f64 serial scan), step, amp
// ---------------------------------------------------------------------------
__global__ __launch_bounds__(64) void f0_kernel(const float* __restrict__ f0s,
    double* __restrict__ based, double* __restrict__ stepd,
    float* __restrict__ ampf)
{
    int b = threadIdx.x;
    if (b >= 4) return;
    double acc = 0.0;
    for (int ft = 0; ft < T_FRAMES; ++ft) {
        double fv = exp((double)f0s[b * T_FRAMES + ft] * 0.25 + 5.0);
        double st = fv / 24000.0;
        based[b * T_FRAMES + ft] = acc;
        stepd[b * T_FRAMES + ft] = st;
        ampf[b * T_FRAMES + ft] = (float)(0.5 * sqrt(24000.0 / fmax(fv, 1.0)));
        acc += 120.0 * st;
    }
}

// ---------------------------------------------------------------------------
// Kernel C: materialize excitation exc[8][24000] (pulse*0.5 | noise*0.5).
// ---------------------------------------------------------------------------
__global__ __launch_bounds__(256) void exc_kernel(
    const double* __restrict__ based, const double* __restrict__ stepd,
    const float* __restrict__ ampf, const float* __restrict__ noise,
    float* __restrict__ exc)
{
    int i = blockIdx.x * 256 + threadIdx.x;
    if (i >= 8 * NSAMP) return;
    int ff = i / NSAMP, n = i - ff * NSAMP;
    int ft = n / HOPW, k = n - ft * HOPW;
    float val;
    if (ff < 4) {
        double st = stepd[ff * T_FRAMES + ft];
        double bs = based[ff * T_FRAMES + ft];
        double ph  = bs + (double)(k + 1) * st;
        double php = bs + (double)k * st;
        val = (floor(ph) > floor(php)) ? ampf[ff * T_FRAMES + ft] : 0.0f;
    } else {
        val = 0.5f * noise[(ff - 4) * NSAMP + n];
    }
    exc[i] = val;
}

// ---------------------------------------------------------------------------
// Single-instruction DPP row-shift (bound_ctrl=true -> 0-fill at row edge;
// round-6's update_dpp(0,...) lowered to 2 instructions per use).
// row_shr:N = 0x110|N, rows are 16 lanes.
// ---------------------------------------------------------------------------
template <int CTRL>
__device__ __forceinline__ float rshr(float x) {
    return __int_as_float(
        __builtin_amdgcn_mov_dpp(__float_as_int(x), CTRL, 0xF, 0xF, true));
}
__device__ __forceinline__ float rlane(float x, int l) {
    return __int_as_float(__builtin_amdgcn_readlane(__float_as_int(x), l));
}

// ---------------------------------------------------------------------------
// Kernel D: MLSA synthesis scan, lane-parallel affine scan (see round 6).
// Wave = one (chunk, filter); block = ONE wave -> no __syncthreads needed
// (lockstep; compiler inserts lgkmcnt for the LDS RAW), which also removes
// the per-frame vmcnt(0) drain of the fire-and-forget output stores.
// ---------------------------------------------------------------------------
__global__ __launch_bounds__(64) void mlsa_kernel(
    const float* __restrict__ bcoef, const float* __restrict__ exc,
    float* __restrict__ y2g)
{
    __shared__ float sexc[HOPW + 2];

    const int tid = threadIdx.x;
    const int i16 = tid & 15;            // position in row
    const int row = tid >> 4;            // Pade tap p
    const int chunk = blockIdx.x >> 3;
    const int f = blockIdx.x & 7;

    const float A = ALPHA;
    const float AA = 1.0f - A * A;
    const float A2 = A * A;
    const float R1 = -(A * A * A);       // (-a)^3
    const float R2 = R1 * R1;
    const float R4 = R2 * R2;
    const float R8 = R4 * R4;
    const float P1 = 0.4999273f, P2 = 0.1067005f, P3 = 0.00956526f, P4 = 0.0003041358f;

    // per-lane seed constant K = r^(i+1)
    float K = R1;
    for (int j = 0; j < i16; ++j) K *= R1;

    // ---- state ----
    float E0 = 0.f, E1 = 0.f, E2 = 0.f;          // delay line d[3i+3..3i+5]
    float dlp = 0.f;                              // dl of previous sample
    float xin = 0.f;                              // pt2 input for this tap
    float d1a1 = 0.f, d1a2 = 0.f, d1a3 = 0.f, d1a4 = 0.f;   // stage-1
    float d1b0 = 0.f, d1b1 = 0.f, d1b2 = 0.f, d1b3 = 0.f;

    const int outF0 = chunk * CHUNKF;

    #pragma unroll 1
    for (int i = 0; i < SERF; ++i) {
        const int ftA = outF0 - WARMF + i;

        // ---- stage excitation for this filter/frame (single wave: no barrier) ----
        for (int j = tid; j < HOPW; j += 64)
            sexc[j] = (ftA >= 0) ? exc[f * NSAMP + ftA * HOPW + j] : 0.f;
        if (tid == 0) sexc[HOPW] = 0.f;

        // ---- frame coefficients (wave-uniform -> scalar loads) ----
        const int ftc = (ftA < 0) ? 0 : ftA;
        const float* bp = bcoef + (f * T_FRAMES + ftc) * M1;
        const float b1 = bp[1];
        const float G  = expf(bp[0]);
        const int ja = 3 * i16 + 2;
        const float Ba = (i16 <= 12) ? bp[ja]     : 0.f;
        const float Bb = (i16 <= 12) ? bp[ja + 1] : 0.f;
        const float Bc = (i16 <= 11) ? bp[ja + 2] : 0.f;
        const bool doOut = (i >= WARMF) && (tid == 0);
        float* yout = y2g + f * NSAMP + ftA * HOPW;

        // ---- sample loop ----
        float xc = sexc[0];
        #pragma unroll 4
        for (int k = 0; k < HOPW; ++k) {
            float xn = sexc[k + 1];
            float x = xc * G;

            // stage 1 (SPTK mlsadf1), identical in all 64 lanes
            float na0 = AA * d1b0 + A * d1a1;
            float na1 = AA * d1b1 + A * d1a2;
            float na2 = AA * d1b2 + A * d1a3;
            float na3 = AA * d1b3 + A * d1a4;
            float n0 = na0 * b1, n1 = na1 * b1, n2 = na2 * b1, n3 = na3 * b1;
            float v10 = n0 * P1, v11 = n1 * P2, v12 = n2 * P3, v13 = n3 * P4;
            float x1 = x + ((v10 - v11) + (v12 - v13));
            float y1 = ((v10 + v11) + (v12 + v13)) + x1;
            d1a1 = na0; d1a2 = na1; d1a3 = na2; d1a4 = na3;
            d1b0 = x1;  d1b1 = n0;  d1b2 = n1;  d1b3 = n2;

            // stage 2: blocked affine scan over the order recurrence
            float pE2 = rshr<0x111>(E2);
            float ca = fmaf(A, E0, (i16 == 0) ? dlp : pE2);
            float cb = fmaf(A, E1, E0);
            float cc = fmaf(A, E2, E1);
            float ua = ca;
            float ub = fmaf(-A, ua, cb);
            float uc = fmaf(-A, ub, cc);
            float X = uc;
            X = fmaf(R1, rshr<0x111>(X), X);
            X = fmaf(R2, rshr<0x112>(X), X);
            X = fmaf(R4, rshr<0x114>(X), X);
            X = fmaf(R8, rshr<0x118>(X), X);
            float dl = fmaf(AA, xin, A * dlp);
            float Xt = fmaf(K, dl, X);                    // true tt_{3i+2}
            float Si = rshr<0x111>(Xt);
            Si = (i16 == 0) ? dl : Si;                    // true tt_{3i-1}
            float ta = fmaf(-A, Si, ua);                  // tt_{3i}
            float tb = fmaf(A2, Si, ub);                  // tt_{3i+1}

            // fy partial + row prefix-sum (total in lanes 15/31/47/63)
            float fp = ta * Ba;
            fp = fmaf(tb, Bb, fp);
            fp = fmaf(Xt, Bc, fp);
            float S = fp;
            S += rshr<0x111>(S);
            S += rshr<0x112>(S);
            S += rshr<0x114>(S);
            S += rshr<0x118>(S);
            float fy0 = rlane(S, 15);
            float fy1 = rlane(S, 31);
            float fy2 = rlane(S, 47);
            float fy3 = rlane(S, 63);

            // cross-tap glue (redundant in all lanes)
            float v20 = fy0 * P1, v21 = fy1 * P2, v22 = fy2 * P3, v23 = fy3 * P4;
            float e = v20 + v22, o = v21 + v23;
            float Tsum = e + o, Usum = e - o;
            float x2 = y1 + Usum;
            float y2 = Tsum + x2;

            // next-sample inputs
            xin = (row == 0) ? x2 : (row == 1) ? fy0 : (row == 2) ? fy1 : fy2;
            E0 = ta; E1 = tb; E2 = Xt;
            dlp = dl;

            if (doOut) yout[k] = y2;
            xc = xn;
        }
    }
}

// ---------------------------------------------------------------------------
// Kernel E: out[b][n] = y2g[b][n] + y2g[4+b][n]
// ---------------------------------------------------------------------------
__global__ __launch_bounds__(256) void combine_kernel(
    const float* __restrict__ y2g, float* __restrict__ out)
{
    int i = blockIdx.x * 256 + threadIdx.x;
    if (i >= 4 * NSAMP) return;
    int b = i / NSAMP, n = i - b * NSAMP;
    out[i] = y2g[b * NSAMP + n] + y2g[(4 + b) * NSAMP + n];
}

// ---------------------------------------------------------------------------
extern "C" void kernel_launch(void* const* d_in, const int* in_sizes, int n_in,
                              void* d_out, int out_size, void* d_ws, size_t ws_size,
                              hipStream_t stream) {
    const float* mceps = (const float*)d_in[0];
    const float* apdcs = (const float*)d_in[1];
    const float* f0s   = (const float*)d_in[2];
    const float* noise = (const float*)d_in[3];
    const float* Wm  = (const float*)d_in[4];
    const float* bm  = (const float*)d_in[5];
    const float* Wa  = (const float*)d_in[6];
    const float* ba  = (const float*)d_in[7];
    const float* Wf  = (const float*)d_in[8];
    const float* bf  = (const float*)d_in[9];
    const float* Wpa = (const float*)d_in[10];
    const float* bpa = (const float*)d_in[11];
    const float* Wpp = (const float*)d_in[12];
    const float* bpp = (const float*)d_in[13];
    const float* Wrp = (const float*)d_in[14];
    const float* brp = (const float*)d_in[15];
    const float* Wra = (const float*)d_in[16];
    const float* bra = (const float*)d_in[17];
    const float* Wap = (const float*)d_in[18];
    float* out = (float*)d_out;

    char* ws = (char*)d_ws;
    double* based = (double*)(ws + 0);          // 6400 B
    double* stepd = (double*)(ws + 6400);       // 6400 B
    float*  ampf  = (float*)(ws + 12800);       // 3200 B
    float*  bcoef = (float*)(ws + 16000);       // 256000 B
    float*  exc   = (float*)(ws + 272000);      // 768000 B
    float*  y2g   = (float*)(ws + 1040000);     // 768000 B  (total 1.81 MB)

    embed_kernel<<<dim3(4 * T_FRAMES / F8), dim3(256), 0, stream>>>(
        mceps, apdcs, f0s, Wm, bm, Wa, ba, Wf, bf,
        Wpa, bpa, Wpp, bpp, Wrp, brp, Wra, bra, Wap, bcoef);

    f0_kernel<<<dim3(1), dim3(64), 0, stream>>>(f0s, based, stepd, ampf);

    exc_kernel<<<dim3((8 * NSAMP + 255) / 256), dim3(256), 0, stream>>>(
        based, stepd, ampf, noise, exc);

    mlsa_kernel<<<dim3(NCHUNK * 8), dim3(64), 0, stream>>>(bcoef, exc, y2g);

    combine_kernel<<<dim3((4 * NSAMP + 255) / 256), dim3(256), 0, stream>>>(
        y2g, out);
}

// Round 8
// 325.905 us; speedup vs baseline: 47.1011x; 1.2537x over previous
//
#include <hip/hip_runtime.h>
#include <math.h>

#define ALPHA 0.466f
#define T_FRAMES 200
#define HOPW 120
#define NSAMP 24000
#define M1 40
#define HID 256
#define CONDW 192

// time-chunking: NCHUNK chunks of CHUNKF output frames, WARMF warm-up frames
// from zero state. One WAVE per (chunk, filter): 100*8 = 800 waves <= 1024
// SIMDs -> at most 1 wave/SIMD.
#define NCHUNK 100
#define CHUNKF 2
#define WARMF 6
#define SERF (WARMF + CHUNKF)   // 8 frames serial per chunk

#define F8 8                     // frames per embed block
#define BPF ((NSAMP + 255) / 256) // 94 exc blocks per filter

// ---------------------------------------------------------------------------
// Kernel A: frame-rate feature MLP + prenets + mc2b  -> bcoef[8][200][40]
// ---------------------------------------------------------------------------
__global__ __launch_bounds__(256) void embed_kernel(
    const float* __restrict__ mceps, const float* __restrict__ apdcs,
    const float* __restrict__ f0s,
    const float* __restrict__ Wm, const float* __restrict__ bm,
    const float* __restrict__ Wa, const float* __restrict__ ba,
    const float* __restrict__ Wf, const float* __restrict__ bf,
    const float* __restrict__ Wpa, const float* __restrict__ bpa,
    const float* __restrict__ Wpp, const float* __restrict__ bpp,
    const float* __restrict__ Wrp, const float* __restrict__ brp,
    const float* __restrict__ Wra, const float* __restrict__ bra,
    const float* __restrict__ Wap, float* __restrict__ bcoef)
{
    __shared__ float s_mc[F8][M1];
    __shared__ float s_ap[F8][5];
    __shared__ float s_f0[F8];
    __shared__ float s_h[F8][HID];
    __shared__ float s_ca[F8][CONDW];
    __shared__ float s_cp[F8][CONDW];
    __shared__ float s_mcp[F8][M1];
    __shared__ float s_mca[F8][M1];

    const int tid = threadIdx.x;
    const int R0 = blockIdx.x * F8;

    for (int j = tid; j < F8 * M1; j += 256) s_mc[j / M1][j % M1] = mceps[R0 * M1 + j];
    if (tid < F8 * 5) s_ap[tid / 5][tid % 5] = apdcs[R0 * 5 + tid];
    if (tid < F8)     s_f0[tid] = f0s[R0 + tid];
    __syncthreads();

    {
        float acc[F8];
        const float bias = bm[tid] + ba[tid] + bf[tid];
        #pragma unroll
        for (int r = 0; r < F8; ++r) acc[r] = bias;
        for (int k = 0; k < M1; ++k) {
            float w = Wm[k * HID + tid];
            #pragma unroll
            for (int r = 0; r < F8; ++r) acc[r] = fmaf(s_mc[r][k], w, acc[r]);
        }
        #pragma unroll
        for (int k = 0; k < 5; ++k) {
            float w = Wa[k * HID + tid];
            #pragma unroll
            for (int r = 0; r < F8; ++r) acc[r] = fmaf(s_ap[r][k], w, acc[r]);
        }
        float wf = Wf[tid];
        #pragma unroll
        for (int r = 0; r < F8; ++r) s_h[r][tid] = fmaf(s_f0[r], wf, acc[r]);
    }
    __syncthreads();

    if (tid < CONDW) {
        float aA[F8], aP[F8];
        #pragma unroll
        for (int r = 0; r < F8; ++r) { aA[r] = bpa[tid]; aP[r] = bpp[tid]; }
        for (int k = 0; k < HID; k += 4) {
            float4 h4[F8];
            #pragma unroll
            for (int r = 0; r < F8; ++r) h4[r] = *(const float4*)&s_h[r][k];
            #pragma unroll
            for (int kk = 0; kk < 4; ++kk) {
                float wa = Wpa[(k + kk) * CONDW + tid];
                float wp = Wpp[(k + kk) * CONDW + tid];
                #pragma unroll
                for (int r = 0; r < F8; ++r) {
                    float hv = (&h4[r].x)[kk];
                    aA[r] = fmaf(hv, wa, aA[r]);
                    aP[r] = fmaf(hv, wp, aP[r]);
                }
            }
        }
        #pragma unroll
        for (int r = 0; r < F8; ++r) { s_ca[r][tid] = aA[r]; s_cp[r][tid] = aP[r]; }
    }
    __syncthreads();

    if (tid < M1) {
        const int u = tid;
        float acc[F8];
        #pragma unroll
        for (int r = 0; r < F8; ++r) acc[r] = brp[u];
        for (int k = 0; k < CONDW; k += 4) {
            float4 c4[F8];
            #pragma unroll
            for (int r = 0; r < F8; ++r) c4[r] = *(const float4*)&s_cp[r][k];
            #pragma unroll
            for (int kk = 0; kk < 4; ++kk) {
                float w = Wrp[(k + kk) * M1 + u];
                #pragma unroll
                for (int r = 0; r < F8; ++r) acc[r] = fmaf((&c4[r].x)[kk], w, acc[r]);
            }
        }
        #pragma unroll
        for (int r = 0; r < F8; ++r)
            s_mcp[r][u] = s_mc[r][u] + 0.1f * tanhf(acc[r]);
    } else if (tid >= 64 && tid < 64 + M1) {
        const int u = tid - 64;
        float acc[F8];
        #pragma unroll
        for (int r = 0; r < F8; ++r) acc[r] = bra[u];
        for (int k = 0; k < CONDW; k += 4) {
            float4 c4[F8];
            #pragma unroll
            for (int r = 0; r < F8; ++r) c4[r] = *(const float4*)&s_ca[r][k];
            #pragma unroll
            for (int kk = 0; kk < 4; ++kk) {
                float w = Wra[(k + kk) * M1 + u];
                #pragma unroll
                for (int r = 0; r < F8; ++r) acc[r] = fmaf((&c4[r].x)[kk], w, acc[r]);
            }
        }
        #pragma unroll
        for (int r = 0; r < F8; ++r) {
            float aw = 0.f;
            #pragma unroll
            for (int j = 0; j < 5; ++j) aw = fmaf(s_ap[r][j], Wap[j * M1 + u], aw);
            s_mca[r][u] = s_mc[r][u] + 0.1f * tanhf(acc[r]) + aw;
        }
    }
    __syncthreads();

    if (tid < 16) {
        const int r = tid >> 1, path = tid & 1;
        const int R = R0 + r;
        const int batch = R / T_FRAMES, t = R - batch * T_FRAMES;
        const float* src = path ? s_mca[r] : s_mcp[r];
        float* dst = bcoef + ((path * 4 + batch) * T_FRAMES + t) * M1;
        float prev = src[M1 - 1];
        dst[M1 - 1] = prev;
        for (int m = M1 - 2; m >= 0; --m) {
            prev = src[m] - ALPHA * prev;
            dst[m] = prev;
        }
    }
}

// ---------------------------------------------------------------------------
// Kernel C: excitation exc[8][24000], f0 prefix fused in.
// Pulse blocks (ff<4) recompute their batch's phase prefix with a 64-lane
// wave-scan (lane = 4 frames; exps parallel across lanes) -- replaces the
// serial 200-iteration f64 f0_kernel (round-7's 2nd-largest kernel).
// ---------------------------------------------------------------------------
__global__ __launch_bounds__(256) void exc_kernel(
    const float* __restrict__ f0s, const float* __restrict__ noise,
    float* __restrict__ exc)
{
    const int ff = blockIdx.x / BPF;
    const int n = (blockIdx.x % BPF) * 256 + threadIdx.x;
    const int tid = threadIdx.x;

    if (ff >= 4) {                       // block-uniform branch
        if (n < NSAMP) exc[ff * NSAMP + n] = 0.5f * noise[(ff - 4) * NSAMP + n];
        return;
    }

    __shared__ double s_base[T_FRAMES];
    __shared__ double s_step[T_FRAMES];
    __shared__ float  s_amp[T_FRAMES];

    if (tid < 64) {
        const int L = tid;
        double st[4], loc[4];
        float am[4];
        double s = 0.0;
        #pragma unroll
        for (int j = 0; j < 4; ++j) {
            int ft = L * 4 + j;
            if (ft < T_FRAMES) {
                double fv = exp((double)f0s[ff * T_FRAMES + ft] * 0.25 + 5.0);
                st[j] = fv / 24000.0;
                am[j] = (float)(0.5 * sqrt(24000.0 / fmax(fv, 1.0)));
            } else { st[j] = 0.0; am[j] = 0.f; }
            loc[j] = s;
            s += st[j];
        }
        double tot = s;
        #pragma unroll
        for (int off = 1; off < 64; off <<= 1) {
            double v = __shfl_up(s, off, 64);
            if (L >= off) s += v;
        }
        double excl = s - tot;           // exclusive prefix of segment sums
        #pragma unroll
        for (int j = 0; j < 4; ++j) {
            int ft = L * 4 + j;
            if (ft < T_FRAMES) {
                s_base[ft] = 120.0 * (excl + loc[j]);
                s_step[ft] = st[j];
                s_amp[ft]  = am[j];
            }
        }
    }
    __syncthreads();

    if (n < NSAMP) {
        int ft = n / HOPW, k = n - ft * HOPW;
        double st = s_step[ft], bs = s_base[ft];
        double ph  = bs + (double)(k + 1) * st;
        double php = bs + (double)k * st;
        exc[ff * NSAMP + n] = (floor(ph) > floor(php)) ? s_amp[ft] : 0.0f;
    }
}

// ---------------------------------------------------------------------------
// DPP row-shift (1 instr; bound_ctrl=true -> 0-fill at row edge).
// ---------------------------------------------------------------------------
template <int CTRL>
__device__ __forceinline__ float rshr(float x) {
    return __int_as_float(
        __builtin_amdgcn_mov_dpp(__float_as_int(x), CTRL, 0xF, 0xF, true));
}
__device__ __forceinline__ float rlane(float x, int l) {
    return __int_as_float(__builtin_amdgcn_readlane(__float_as_int(x), l));
}

// ---------------------------------------------------------------------------
// One frame of the lane-parallel MLSA scan. OUT frames store y2 (tid 0);
// warm frames skip the store AND the Tsum/y2 glue (-~6 instr/sample).
// ---------------------------------------------------------------------------
template <bool OUT>
__device__ __forceinline__ void run_frame(
    const float* __restrict__ sx, float G, float b1,
    float Ba, float Bb, float Bc, float K, int i16, int row, int tid,
    float& E0, float& E1, float& E2, float& dlp, float& xin,
    float& d1a1, float& d1a2, float& d1a3, float& d1a4,
    float& d1b0, float& d1b1, float& d1b2, float& d1b3,
    float* __restrict__ yout)
{
    const float A = ALPHA;
    const float AA = 1.0f - A * A;
    const float A2 = A * A;
    const float R1 = -(A * A * A);
    const float R2 = R1 * R1;
    const float R4 = R2 * R2;
    const float R8 = R4 * R4;
    const float P1 = 0.4999273f, P2 = 0.1067005f, P3 = 0.00956526f, P4 = 0.0003041358f;

    float xc = sx[0];
    #pragma unroll 8
    for (int k = 0; k < HOPW; ++k) {
        float xn = sx[k + 1];
        float x = xc * G;

        // stage 1 (SPTK mlsadf1), identical in all 64 lanes
        float na0 = AA * d1b0 + A * d1a1;
        float na1 = AA * d1b1 + A * d1a2;
        float na2 = AA * d1b2 + A * d1a3;
        float na3 = AA * d1b3 + A * d1a4;
        float n0 = na0 * b1, n1 = na1 * b1, n2 = na2 * b1, n3 = na3 * b1;
        float v10 = n0 * P1, v11 = n1 * P2, v12 = n2 * P3, v13 = n3 * P4;
        float x1 = x + ((v10 - v11) + (v12 - v13));
        float y1 = ((v10 + v11) + (v12 + v13)) + x1;
        d1a1 = na0; d1a2 = na1; d1a3 = na2; d1a4 = na3;
        d1b0 = x1;  d1b1 = n0;  d1b2 = n1;  d1b3 = n2;

        // stage 2: blocked affine scan over the order recurrence
        float pE2 = rshr<0x111>(E2);
        float ca = fmaf(A, E0, (i16 == 0) ? dlp : pE2);
        float cb = fmaf(A, E1, E0);
        float cc = fmaf(A, E2, E1);
        float ua = ca;
        float ub = fmaf(-A, ua, cb);
        float uc = fmaf(-A, ub, cc);
        float X = uc;
        X = fmaf(R1, rshr<0x111>(X), X);
        X = fmaf(R2, rshr<0x112>(X), X);
        X = fmaf(R4, rshr<0x114>(X), X);
        X = fmaf(R8, rshr<0x118>(X), X);
        float dl = fmaf(AA, xin, A * dlp);
        float Xt = fmaf(K, dl, X);                    // true tt_{3i+2}
        float Si = rshr<0x111>(Xt);
        Si = (i16 == 0) ? dl : Si;                    // true tt_{3i-1}
        float ta = fmaf(-A, Si, ua);                  // tt_{3i}
        float tb = fmaf(A2, Si, ub);                  // tt_{3i+1}

        // fy partial + row prefix-sum (totals in lanes 15/31/47/63)
        float fp = ta * Ba;
        fp = fmaf(tb, Bb, fp);
        fp = fmaf(Xt, Bc, fp);
        float S = fp;
        S += rshr<0x111>(S);
        S += rshr<0x112>(S);
        S += rshr<0x114>(S);
        S += rshr<0x118>(S);
        float fy0 = rlane(S, 15);
        float fy1 = rlane(S, 31);
        float fy2 = rlane(S, 47);
        float fy3 = rlane(S, 63);

        // cross-tap glue
        float v20 = fy0 * P1, v21 = fy1 * P2, v22 = fy2 * P3, v23 = fy3 * P4;
        float e = v20 + v22, o = v21 + v23;
        float Usum = e - o;
        float x2 = y1 + Usum;
        if (OUT) {
            float y2 = (e + o) + x2;
            if (tid == 0) yout[k] = y2;
        }

        // next-sample inputs
        xin = (row == 0) ? x2 : (row == 1) ? fy0 : (row == 2) ? fy1 : fy2;
        E0 = ta; E1 = tb; E2 = Xt;
        dlp = dl;
        xc = xn;
    }
}

// ---------------------------------------------------------------------------
// Kernel D: MLSA synthesis scan (block = one wave = one (chunk, filter)).
// ---------------------------------------------------------------------------
__global__ __launch_bounds__(64) void mlsa_kernel(
    const float* __restrict__ bcoef, const float* __restrict__ exc,
    float* __restrict__ y2g)
{
    __shared__ float sexc[HOPW + 2];

    const int tid = threadIdx.x;
    const int i16 = tid & 15;
    const int row = tid >> 4;
    const int chunk = blockIdx.x >> 3;
    const int f = blockIdx.x & 7;

    const float R1 = -(ALPHA * ALPHA * ALPHA);
    float K = R1;
    for (int j = 0; j < i16; ++j) K *= R1;

    float E0 = 0.f, E1 = 0.f, E2 = 0.f;
    float dlp = 0.f, xin = 0.f;
    float d1a1 = 0.f, d1a2 = 0.f, d1a3 = 0.f, d1a4 = 0.f;
    float d1b0 = 0.f, d1b1 = 0.f, d1b2 = 0.f, d1b3 = 0.f;

    const int outF0 = chunk * CHUNKF;

    #pragma unroll 1
    for (int i = 0; i < SERF; ++i) {
        const int ftA = outF0 - WARMF + i;

        for (int j = tid; j < HOPW; j += 64)
            sexc[j] = (ftA >= 0) ? exc[f * NSAMP + ftA * HOPW + j] : 0.f;
        if (tid == 0) sexc[HOPW] = 0.f;

        const int ftc = (ftA < 0) ? 0 : ftA;
        const float* bp = bcoef + (f * T_FRAMES + ftc) * M1;
        const float b1 = bp[1];
        const float G  = expf(bp[0]);
        const int ja = 3 * i16 + 2;
        const float Ba = (i16 <= 12) ? bp[ja]     : 0.f;
        const float Bb = (i16 <= 12) ? bp[ja + 1] : 0.f;
        const float Bc = (i16 <= 11) ? bp[ja + 2] : 0.f;
        float* yout = y2g + f * NSAMP + ftA * HOPW;

        if (i >= WARMF)
            run_frame<true>(sexc, G, b1, Ba, Bb, Bc, K, i16, row, tid,
                            E0, E1, E2, dlp, xin,
                            d1a1, d1a2, d1a3, d1a4, d1b0, d1b1, d1b2, d1b3, yout);
        else
            run_frame<false>(sexc, G, b1, Ba, Bb, Bc, K, i16, row, tid,
                             E0, E1, E2, dlp, xin,
                             d1a1, d1a2, d1a3, d1a4, d1b0, d1b1, d1b2, d1b3, yout);
    }
}

// ---------------------------------------------------------------------------
// Kernel E: out[b][n] = y2g[b][n] + y2g[4+b][n]
// ---------------------------------------------------------------------------
__global__ __launch_bounds__(256) void combine_kernel(
    const float* __restrict__ y2g, float* __restrict__ out)
{
    int i = blockIdx.x * 256 + threadIdx.x;
    if (i >= 4 * NSAMP) return;
    int b = i / NSAMP, n = i - b * NSAMP;
    out[i] = y2g[b * NSAMP + n] + y2g[(4 + b) * NSAMP + n];
}

// ---------------------------------------------------------------------------
extern "C" void kernel_launch(void* const* d_in, const int* in_sizes, int n_in,
                              void* d_out, int out_size, void* d_ws, size_t ws_size,
                              hipStream_t stream) {
    const float* mceps = (const float*)d_in[0];
    const float* apdcs = (const float*)d_in[1];
    const float* f0s   = (const float*)d_in[2];
    const float* noise = (const float*)d_in[3];
    const float* Wm  = (const float*)d_in[4];
    const float* bm  = (const float*)d_in[5];
    const float* Wa  = (const float*)d_in[6];
    const float* ba  = (const float*)d_in[7];
    const float* Wf  = (const float*)d_in[8];
    const float* bf  = (const float*)d_in[9];
    const float* Wpa = (const float*)d_in[10];
    const float* bpa = (const float*)d_in[11];
    const float* Wpp = (const float*)d_in[12];
    const float* bpp = (const float*)d_in[13];
    const float* Wrp = (const float*)d_in[14];
    const float* brp = (const float*)d_in[15];
    const float* Wra = (const float*)d_in[16];
    const float* bra = (const float*)d_in[17];
    const float* Wap = (const float*)d_in[18];
    float* out = (float*)d_out;

    char* ws = (char*)d_ws;
    float* bcoef = (float*)(ws + 0);           // 256000 B
    float* exc   = (float*)(ws + 256000);      // 768000 B
    float* y2g   = (float*)(ws + 1024000);     // 768000 B

    embed_kernel<<<dim3(4 * T_FRAMES / F8), dim3(256), 0, stream>>>(
        mceps, apdcs, f0s, Wm, bm, Wa, ba, Wf, bf,
        Wpa, bpa, Wpp, bpp, Wrp, brp, Wra, bra, Wap, bcoef);

    exc_kernel<<<dim3(8 * BPF), dim3(256), 0, stream>>>(f0s, noise, exc);

    mlsa_kernel<<<dim3(NCHUNK * 8), dim3(64), 0, stream>>>(bcoef, exc, y2g);

    combine_kernel<<<dim3((4 * NSAMP + 255) / 256), dim3(256), 0, stream>>>(
        y2g, out);
}

// Round 9
// 221.923 us; speedup vs baseline: 69.1703x; 1.4685x over previous
//
#include <hip/hip_runtime.h>
#include <math.h>

#define ALPHA 0.466f
#define T_FRAMES 200
#define HOPW 120
#define NSAMP 24000
#define M1 40
#define HID 256
#define CONDW 192

// time-chunking: NCHUNK chunks of CHUNKF output frames, WARMF warm-up frames
// from zero state. One WAVE per (chunk, filter): 100*8 = 800 waves <= 1024
// SIMDs -> at most 1 wave/SIMD. absmax bit-identical WARMF=20..6 -> 4 keeps
// 2x margin over the proven-identical 8.
#define NCHUNK 100
#define CHUNKF 2
#define WARMF 4
#define SERF (WARMF + CHUNKF)   // 6 frames serial per chunk

#define F8 8                     // frames per embed block
#define BPF ((NSAMP + 255) / 256) // exc blocks per filter

// ---------------------------------------------------------------------------
// Kernel A: frame-rate feature MLP + prenets + mc2b  -> bcoef[8][200][40]
// ---------------------------------------------------------------------------
__global__ __launch_bounds__(256) void embed_kernel(
    const float* __restrict__ mceps, const float* __restrict__ apdcs,
    const float* __restrict__ f0s,
    const float* __restrict__ Wm, const float* __restrict__ bm,
    const float* __restrict__ Wa, const float* __restrict__ ba,
    const float* __restrict__ Wf, const float* __restrict__ bf,
    const float* __restrict__ Wpa, const float* __restrict__ bpa,
    const float* __restrict__ Wpp, const float* __restrict__ bpp,
    const float* __restrict__ Wrp, const float* __restrict__ brp,
    const float* __restrict__ Wra, const float* __restrict__ bra,
    const float* __restrict__ Wap, float* __restrict__ bcoef)
{
    __shared__ float s_mc[F8][M1];
    __shared__ float s_ap[F8][5];
    __shared__ float s_f0[F8];
    __shared__ float s_h[F8][HID];
    __shared__ float s_ca[F8][CONDW];
    __shared__ float s_cp[F8][CONDW];
    __shared__ float s_mcp[F8][M1];
    __shared__ float s_mca[F8][M1];

    const int tid = threadIdx.x;
    const int R0 = blockIdx.x * F8;

    for (int j = tid; j < F8 * M1; j += 256) s_mc[j / M1][j % M1] = mceps[R0 * M1 + j];
    if (tid < F8 * 5) s_ap[tid / 5][tid % 5] = apdcs[R0 * 5 + tid];
    if (tid < F8)     s_f0[tid] = f0s[R0 + tid];
    __syncthreads();

    {
        float acc[F8];
        const float bias = bm[tid] + ba[tid] + bf[tid];
        #pragma unroll
        for (int r = 0; r < F8; ++r) acc[r] = bias;
        for (int k = 0; k < M1; ++k) {
            float w = Wm[k * HID + tid];
            #pragma unroll
            for (int r = 0; r < F8; ++r) acc[r] = fmaf(s_mc[r][k], w, acc[r]);
        }
        #pragma unroll
        for (int k = 0; k < 5; ++k) {
            float w = Wa[k * HID + tid];
            #pragma unroll
            for (int r = 0; r < F8; ++r) acc[r] = fmaf(s_ap[r][k], w, acc[r]);
        }
        float wf = Wf[tid];
        #pragma unroll
        for (int r = 0; r < F8; ++r) s_h[r][tid] = fmaf(s_f0[r], wf, acc[r]);
    }
    __syncthreads();

    if (tid < CONDW) {
        float aA[F8], aP[F8];
        #pragma unroll
        for (int r = 0; r < F8; ++r) { aA[r] = bpa[tid]; aP[r] = bpp[tid]; }
        for (int k = 0; k < HID; k += 4) {
            float4 h4[F8];
            #pragma unroll
            for (int r = 0; r < F8; ++r) h4[r] = *(const float4*)&s_h[r][k];
            #pragma unroll
            for (int kk = 0; kk < 4; ++kk) {
                float wa = Wpa[(k + kk) * CONDW + tid];
                float wp = Wpp[(k + kk) * CONDW + tid];
                #pragma unroll
                for (int r = 0; r < F8; ++r) {
                    float hv = (&h4[r].x)[kk];
                    aA[r] = fmaf(hv, wa, aA[r]);
                    aP[r] = fmaf(hv, wp, aP[r]);
                }
            }
        }
        #pragma unroll
        for (int r = 0; r < F8; ++r) { s_ca[r][tid] = aA[r]; s_cp[r][tid] = aP[r]; }
    }
    __syncthreads();

    if (tid < M1) {
        const int u = tid;
        float acc[F8];
        #pragma unroll
        for (int r = 0; r < F8; ++r) acc[r] = brp[u];
        for (int k = 0; k < CONDW; k += 4) {
            float4 c4[F8];
            #pragma unroll
            for (int r = 0; r < F8; ++r) c4[r] = *(const float4*)&s_cp[r][k];
            #pragma unroll
            for (int kk = 0; kk < 4; ++kk) {
                float w = Wrp[(k + kk) * M1 + u];
                #pragma unroll
                for (int r = 0; r < F8; ++r) acc[r] = fmaf((&c4[r].x)[kk], w, acc[r]);
            }
        }
        #pragma unroll
        for (int r = 0; r < F8; ++r)
            s_mcp[r][u] = s_mc[r][u] + 0.1f * tanhf(acc[r]);
    } else if (tid >= 64 && tid < 64 + M1) {
        const int u = tid - 64;
        float acc[F8];
        #pragma unroll
        for (int r = 0; r < F8; ++r) acc[r] = bra[u];
        for (int k = 0; k < CONDW; k += 4) {
            float4 c4[F8];
            #pragma unroll
            for (int r = 0; r < F8; ++r) c4[r] = *(const float4*)&s_ca[r][k];
            #pragma unroll
            for (int kk = 0; kk < 4; ++kk) {
                float w = Wra[(k + kk) * M1 + u];
                #pragma unroll
                for (int r = 0; r < F8; ++r) acc[r] = fmaf((&c4[r].x)[kk], w, acc[r]);
            }
        }
        #pragma unroll
        for (int r = 0; r < F8; ++r) {
            float aw = 0.f;
            #pragma unroll
            for (int j = 0; j < 5; ++j) aw = fmaf(s_ap[r][j], Wap[j * M1 + u], aw);
            s_mca[r][u] = s_mc[r][u] + 0.1f * tanhf(acc[r]) + aw;
        }
    }
    __syncthreads();

    if (tid < 16) {
        const int r = tid >> 1, path = tid & 1;
        const int R = R0 + r;
        const int batch = R / T_FRAMES, t = R - batch * T_FRAMES;
        const float* src = path ? s_mca[r] : s_mcp[r];
        float* dst = bcoef + ((path * 4 + batch) * T_FRAMES + t) * M1;
        float prev = src[M1 - 1];
        dst[M1 - 1] = prev;
        for (int m = M1 - 2; m >= 0; --m) {
            prev = src[m] - ALPHA * prev;
            dst[m] = prev;
        }
    }
}

// ---------------------------------------------------------------------------
// Kernel C: excitation exc[8][24000], f0 prefix fused in (64-lane wave scan).
// ---------------------------------------------------------------------------
__global__ __launch_bounds__(256) void exc_kernel(
    const float* __restrict__ f0s, const float* __restrict__ noise,
    float* __restrict__ exc)
{
    const int ff = blockIdx.x / BPF;
    const int n = (blockIdx.x % BPF) * 256 + threadIdx.x;
    const int tid = threadIdx.x;

    if (ff >= 4) {
        if (n < NSAMP) exc[ff * NSAMP + n] = 0.5f * noise[(ff - 4) * NSAMP + n];
        return;
    }

    __shared__ double s_base[T_FRAMES];
    __shared__ double s_step[T_FRAMES];
    __shared__ float  s_amp[T_FRAMES];

    if (tid < 64) {
        const int L = tid;
        double st[4], loc[4];
        float am[4];
        double s = 0.0;
        #pragma unroll
        for (int j = 0; j < 4; ++j) {
            int ft = L * 4 + j;
            if (ft < T_FRAMES) {
                double fv = exp((double)f0s[ff * T_FRAMES + ft] * 0.25 + 5.0);
                st[j] = fv / 24000.0;
                am[j] = (float)(0.5 * sqrt(24000.0 / fmax(fv, 1.0)));
            } else { st[j] = 0.0; am[j] = 0.f; }
            loc[j] = s;
            s += st[j];
        }
        double tot = s;
        #pragma unroll
        for (int off = 1; off < 64; off <<= 1) {
            double v = __shfl_up(s, off, 64);
            if (L >= off) s += v;
        }
        double excl = s - tot;
        #pragma unroll
        for (int j = 0; j < 4; ++j) {
            int ft = L * 4 + j;
            if (ft < T_FRAMES) {
                s_base[ft] = 120.0 * (excl + loc[j]);
                s_step[ft] = st[j];
                s_amp[ft]  = am[j];
            }
        }
    }
    __syncthreads();

    if (n < NSAMP) {
        int ft = n / HOPW, k = n - ft * HOPW;
        double st = s_step[ft], bs = s_base[ft];
        double ph  = bs + (double)(k + 1) * st;
        double php = bs + (double)k * st;
        exc[ff * NSAMP + n] = (floor(ph) > floor(php)) ? s_amp[ft] : 0.0f;
    }
}

// ---------------------------------------------------------------------------
// DPP helpers. row_shr:N = 0x110|N; row_bcast15 = 0x142 (lane15->lanes16-31,
// lane31->32-47, lane47->48-63; bound_ctrl=1 -> lanes 0-15 read 0).
// ---------------------------------------------------------------------------
template <int CTRL>
__device__ __forceinline__ float rshr(float x) {
    return __int_as_float(
        __builtin_amdgcn_mov_dpp(__float_as_int(x), CTRL, 0xF, 0xF, true));
}
__device__ __forceinline__ float rlane(float x, int l) {
    return __int_as_float(__builtin_amdgcn_readlane(__float_as_int(x), l));
}

// ---------------------------------------------------------------------------
// One frame of the lane-parallel MLSA scan.
// Pade weights are FOLDED into Ba/Bb/Bc (per frame), so the row totals are
// v2_r directly; xin for rows 1-3 comes from row_bcast15 scaled by IPw
// (= 1/P_row). Excitation is pre-scaled by G during staging. Stage 1 uses
// b1-folded constants (AB = AA*b1, BPi = b1*Pi): state m1..m4 (= prev na),
// w0 (= prev x1).
// ---------------------------------------------------------------------------
template <bool OUT>
__device__ __forceinline__ void run_frame(
    const float* __restrict__ sx, float AB,
    float BP1, float BP2, float BP3, float BP4,
    float Ba, float Bb, float Bc, float K, float IPw, int i16, int row,
    float& E0, float& E1, float& E2, float& dlp, float& xin,
    float& m1, float& m2, float& m3, float& m4, float& w0,
    float* __restrict__ yout)
{
    const float A = ALPHA;
    const float AA = 1.0f - A * A;
    const float A2 = A * A;
    const float R1 = -(A * A * A);
    const float R2 = R1 * R1;
    const float R4 = R2 * R2;
    const float R8 = R4 * R4;

    float xc = sx[0];
    #pragma unroll 8
    for (int k = 0; k < HOPW; ++k) {
        float xn = sx[k + 1];
        float x = xc;                                  // G pre-folded

        // stage 1 (SPTK mlsadf1), b1-rescaled, identical in all 64 lanes
        float na0 = AA * w0 + A * m1;
        float na1 = AB * m1 + A * m2;
        float na2 = AB * m2 + A * m3;
        float na3 = AB * m3 + A * m4;
        float v10 = na0 * BP1, v11 = na1 * BP2, v12 = na2 * BP3, v13 = na3 * BP4;
        float x1 = x + ((v10 - v11) + (v12 - v13));
        float y1 = ((v10 + v11) + (v12 + v13)) + x1;
        m1 = na0; m2 = na1; m3 = na2; m4 = na3; w0 = x1;

        // stage 2: blocked affine scan over the order recurrence
        float pE2 = rshr<0x111>(E2);
        float ca = fmaf(A, E0, (i16 == 0) ? dlp : pE2);
        float cb = fmaf(A, E1, E0);
        float cc = fmaf(A, E2, E1);
        float ua = ca;
        float ub = fmaf(-A, ua, cb);
        float uc = fmaf(-A, ub, cc);
        float X = uc;
        X = fmaf(R1, rshr<0x111>(X), X);
        X = fmaf(R2, rshr<0x112>(X), X);
        X = fmaf(R4, rshr<0x114>(X), X);
        X = fmaf(R8, rshr<0x118>(X), X);
        float dl = fmaf(AA, xin, A * dlp);
        float Xt = fmaf(K, dl, X);                    // true tt_{3i+2}
        float Si = rshr<0x111>(Xt);
        Si = (i16 == 0) ? dl : Si;                    // true tt_{3i-1}
        float ta = fmaf(-A, Si, ua);                  // tt_{3i}
        float tb = fmaf(A2, Si, ub);                  // tt_{3i+1}

        // P-weighted fy partial + row prefix-sum -> row totals ARE v2_r
        float fp = ta * Ba;
        fp = fmaf(tb, Bb, fp);
        fp = fmaf(Xt, Bc, fp);
        float S = fp;
        S += rshr<0x111>(S);
        S += rshr<0x112>(S);
        S += rshr<0x114>(S);
        S += rshr<0x118>(S);

        // xin for rows 1-3: previous row's total * (1/P_row), one DPP
        float xprev = rshr<0x142>(S) * IPw;

        // glue (v2 totals via readlane; only row0/lane0 consume, SIMT anyway)
        float v20 = rlane(S, 15);
        float v21 = rlane(S, 31);
        float v22 = rlane(S, 47);
        float v23 = rlane(S, 63);
        float e = v20 + v22, o = v21 + v23;
        float x2 = y1 + (e - o);
        if (OUT) {
            float y2 = (e + o) + x2;
            yout[k] = y2;                             // all lanes, same value
        }

        // next-sample inputs
        xin = (row == 0) ? x2 : xprev;
        E0 = ta; E1 = tb; E2 = Xt;
        dlp = dl;
        xc = xn;
    }
}

// ---------------------------------------------------------------------------
// Kernel D: MLSA synthesis scan (block = one wave = one (chunk, filter)).
// ---------------------------------------------------------------------------
__global__ __launch_bounds__(64) void mlsa_kernel(
    const float* __restrict__ bcoef, const float* __restrict__ exc,
    float* __restrict__ y2g)
{
    __shared__ float sexc[HOPW + 2];

    const int tid = threadIdx.x;
    const int i16 = tid & 15;
    const int row = tid >> 4;
    const int chunk = blockIdx.x >> 3;
    const int f = blockIdx.x & 7;

    const float P1 = 0.4999273f, P2 = 0.1067005f, P3 = 0.00956526f, P4 = 0.0003041358f;
    const float Pw  = (row == 0) ? P1 : (row == 1) ? P2 : (row == 2) ? P3 : P4;
    const float IPw = (row == 1) ? (1.f / P1) : (row == 2) ? (1.f / P2) : (1.f / P3);

    const float R1 = -(ALPHA * ALPHA * ALPHA);
    float K = R1;
    for (int j = 0; j < i16; ++j) K *= R1;

    float E0 = 0.f, E1 = 0.f, E2 = 0.f;
    float dlp = 0.f, xin = 0.f;
    float m1 = 0.f, m2 = 0.f, m3 = 0.f, m4 = 0.f, w0 = 0.f;

    const int outF0 = chunk * CHUNKF;

    #pragma unroll 1
    for (int i = 0; i < SERF; ++i) {
        const int ftA = outF0 - WARMF + i;

        const int ftc = (ftA < 0) ? 0 : ftA;
        const float* bp = bcoef + (f * T_FRAMES + ftc) * M1;
        const float b1 = bp[1];
        const float G  = expf(bp[0]);
        const float AA = 1.0f - ALPHA * ALPHA;
        const float AB = AA * b1;
        const float BP1 = b1 * P1, BP2 = b1 * P2, BP3 = b1 * P3, BP4 = b1 * P4;

        // stage excitation, pre-scaled by G (single wave: no barrier needed)
        for (int j = tid; j < HOPW; j += 64)
            sexc[j] = (ftA >= 0) ? exc[f * NSAMP + ftA * HOPW + j] * G : 0.f;
        if (tid == 0) sexc[HOPW] = 0.f;

        // Pade-weighted FIR coefficients (per lane)
        const int ja = 3 * i16 + 2;
        const float Ba = ((i16 <= 12) ? bp[ja]     : 0.f) * Pw;
        const float Bb = ((i16 <= 12) ? bp[ja + 1] : 0.f) * Pw;
        const float Bc = ((i16 <= 11) ? bp[ja + 2] : 0.f) * Pw;
        float* yout = y2g + f * NSAMP + ftA * HOPW;

        if (i >= WARMF)
            run_frame<true>(sexc, AB, BP1, BP2, BP3, BP4, Ba, Bb, Bc, K, IPw,
                            i16, row, E0, E1, E2, dlp, xin, m1, m2, m3, m4, w0, yout);
        else
            run_frame<false>(sexc, AB, BP1, BP2, BP3, BP4, Ba, Bb, Bc, K, IPw,
                             i16, row, E0, E1, E2, dlp, xin, m1, m2, m3, m4, w0, yout);
    }
}

// ---------------------------------------------------------------------------
// Kernel E: out[b][n] = y2g[b][n] + y2g[4+b][n]
// ---------------------------------------------------------------------------
__global__ __launch_bounds__(256) void combine_kernel(
    const float* __restrict__ y2g, float* __restrict__ out)
{
    int i = blockIdx.x * 256 + threadIdx.x;
    if (i >= 4 * NSAMP) return;
    int b = i / NSAMP, n = i - b * NSAMP;
    out[i] = y2g[b * NSAMP + n] + y2g[(4 + b) * NSAMP + n];
}

// ---------------------------------------------------------------------------
extern "C" void kernel_launch(void* const* d_in, const int* in_sizes, int n_in,
                              void* d_out, int out_size, void* d_ws, size_t ws_size,
                              hipStream_t stream) {
    const float* mceps = (const float*)d_in[0];
    const float* apdcs = (const float*)d_in[1];
    const float* f0s   = (const float*)d_in[2];
    const float* noise = (const float*)d_in[3];
    const float* Wm  = (const float*)d_in[4];
    const float* bm  = (const float*)d_in[5];
    const float* Wa  = (const float*)d_in[6];
    const float* ba  = (const float*)d_in[7];
    const float* Wf  = (const float*)d_in[8];
    const float* bf  = (const float*)d_in[9];
    const float* Wpa = (const float*)d_in[10];
    const float* bpa = (const float*)d_in[11];
    const float* Wpp = (const float*)d_in[12];
    const float* bpp = (const float*)d_in[13];
    const float* Wrp = (const float*)d_in[14];
    const float* brp = (const float*)d_in[15];
    const float* Wra = (const float*)d_in[16];
    const float* bra = (const float*)d_in[17];
    const float* Wap = (const float*)d_in[18];
    float* out = (float*)d_out;

    char* ws = (char*)d_ws;
    float* bcoef = (float*)(ws + 0);           // 256000 B
    float* exc   = (float*)(ws + 256000);      // 768000 B
    float* y2g   = (float*)(ws + 1024000);     // 768000 B

    embed_kernel<<<dim3(4 * T_FRAMES / F8), dim3(256), 0, stream>>>(
        mceps, apdcs, f0s, Wm, bm, Wa, ba, Wf, bf,
        Wpa, bpa, Wpp, bpp, Wrp, brp, Wra, bra, Wap, bcoef);

    exc_kernel<<<dim3(8 * BPF), dim3(256), 0, stream>>>(f0s, noise, exc);

    mlsa_kernel<<<dim3(NCHUNK * 8), dim3(64), 0, stream>>>(bcoef, exc, y2g);

    combine_kernel<<<dim3((4 * NSAMP + 255) / 256), dim3(256), 0, stream>>>(
        y2g, out);
}